// Round 1
// baseline (1360.643 us; speedup 1.0000x reference)
//
#include <hip/hip_runtime.h>
#include <hip/hip_bf16.h>
#include <math.h>

#define HEADS 8
#define NTOK  2304
#define DH    64
#define QD    320
#define INNER 512
#define NTILE 36   // NTOK / 64

// ---------------------------------------------------------------------------
// Kernel A: q_blend[h][n][d] = 0.5*q_injected + 0.5*(x @ Wq) split to heads
// ---------------------------------------------------------------------------
__global__ __launch_bounds__(256) void gemm_qblend(
    const float* __restrict__ x, const float* __restrict__ Wq,
    const float* __restrict__ qinj, float* __restrict__ qb)
{
  __shared__ float As[32][68];   // [k][r] (transposed x tile)
  __shared__ float Bs[32][68];   // [k][c]
  const int n0 = blockIdx.x * 64;
  const int h  = blockIdx.y;
  const int o0 = h * 64;
  const int tid = threadIdx.x;
  const int ty = tid >> 4, tx = tid & 15;
  const int r0 = ty * 4, c0 = tx * 4;
  float acc[4][4] = {};
  for (int k0 = 0; k0 < QD; k0 += 32) {
    for (int idx = tid; idx < 64 * 32; idx += 256) {
      int r = idx >> 5, kk = idx & 31;
      As[kk][r] = x[(size_t)(n0 + r) * QD + k0 + kk];
    }
    for (int idx = tid; idx < 32 * 64; idx += 256) {
      int kk = idx >> 6, c = idx & 63;
      Bs[kk][c] = Wq[(size_t)(k0 + kk) * INNER + o0 + c];
    }
    __syncthreads();
    #pragma unroll
    for (int kk = 0; kk < 32; ++kk) {
      float4 a = *reinterpret_cast<const float4*>(&As[kk][r0]);
      float4 b = *reinterpret_cast<const float4*>(&Bs[kk][c0]);
      float av[4] = {a.x, a.y, a.z, a.w};
      float bv[4] = {b.x, b.y, b.z, b.w};
      #pragma unroll
      for (int i = 0; i < 4; ++i)
        #pragma unroll
        for (int j = 0; j < 4; ++j) acc[i][j] += av[i] * bv[j];
    }
    __syncthreads();
  }
  #pragma unroll
  for (int i = 0; i < 4; ++i) {
    int n = n0 + r0 + i;
    size_t base = ((size_t)h * NTOK + n) * DH + c0;
    float4 qi = *reinterpret_cast<const float4*>(&qinj[base]);
    float4 o;
    o.x = 0.5f * qi.x + 0.5f * acc[i][0];
    o.y = 0.5f * qi.y + 0.5f * acc[i][1];
    o.z = 0.5f * qi.z + 0.5f * acc[i][2];
    o.w = 0.5f * qi.w + 0.5f * acc[i][3];
    *reinterpret_cast<float4*>(&qb[base]) = o;
  }
}

// ---------------------------------------------------------------------------
// Kernel B: fused attention (3 sims + gvm + concatenated online softmax + PV)
// one block = (head h, 64 query rows); loops over 36 key tiles of 64
// ---------------------------------------------------------------------------
__global__ __launch_bounds__(256, 1) void attn_fused(
    const float* __restrict__ qb,   // blended q   [h][n][d]
    const float* __restrict__ kst,  // k_injected  (style keys)
    const float* __restrict__ vst,  // v_injected  (style values)
    const float* __restrict__ qct,  // q_injected  (content q = q_in)
    const float* __restrict__ kct,  // cnt_k_injected
    const float* __restrict__ vct,  // cnt_v_injected
    const float* __restrict__ mask, // [48*48]
    float* __restrict__ mid)        // [n][h*64+d]
{
  __shared__ float Qs [64][68];  // [d][r]
  __shared__ float QCs[64][68];  // [d][r]
  __shared__ float KA [64][68];  // scores: K^T [d][j]   | PV: V    [j][d]
  __shared__ float KB [64][68];  // scores: Kc^T [d][j]  | PV: Vcnt [j][d]
  __shared__ float P1 [64][68];  // [j][r]
  __shared__ float P2 [64][68];  // [j][r]

  const int qt = blockIdx.x, h = blockIdx.y;
  const int n0 = qt * 64;
  const int tid = threadIdx.x;
  const int ty = tid >> 4, tx = tid & 15;
  const int r0 = ty * 4, c0 = tx * 4;
  const size_t hbase = (size_t)h * NTOK * DH;

  // stage Q tiles (transposed)
  for (int idx = tid; idx < 64 * 64; idx += 256) {
    int r = idx >> 6, d = idx & 63;
    Qs [d][r] = qb [hbase + (size_t)(n0 + r) * DH + d];
    QCs[d][r] = qct[hbase + (size_t)(n0 + r) * DH + d];
  }

  float O1[4][4] = {}, O2[4][4] = {};
  float M1[4], S1[4] = {}, M2[4], S2[4] = {};
  float mnCC[4], mxMS[4];
  #pragma unroll
  for (int i = 0; i < 4; ++i) {
    M1[i] = -INFINITY; M2[i] = -INFINITY;
    mnCC[i] = INFINITY; mxMS[i] = -INFINITY;
  }

  for (int jt = 0; jt < NTILE; ++jt) {
    const int j0 = jt * 64;
    // stage K^T / Kcnt^T (overwrites last tile's V — guarded by loop-end barrier)
    for (int idx = tid; idx < 64 * 64; idx += 256) {
      int j = idx >> 6, d = idx & 63;
      KA[d][j] = kst[hbase + (size_t)(j0 + j) * DH + d];
      KB[d][j] = kct[hbase + (size_t)(j0 + j) * DH + d];
    }
    __syncthreads();  // (A) K staged (covers Q stage on first iter)

    float s1[4][4] = {}, s2[4][4] = {}, s3[4][4] = {};  // sim, cc, ms
    #pragma unroll 8
    for (int d = 0; d < 64; ++d) {
      float4 qv = *reinterpret_cast<const float4*>(&Qs [d][r0]);
      float4 qc = *reinterpret_cast<const float4*>(&QCs[d][r0]);
      float4 kv = *reinterpret_cast<const float4*>(&KA [d][c0]);
      float4 kc = *reinterpret_cast<const float4*>(&KB [d][c0]);
      float qa[4]  = {qv.x, qv.y, qv.z, qv.w};
      float qca[4] = {qc.x, qc.y, qc.z, qc.w};
      float ka[4]  = {kv.x, kv.y, kv.z, kv.w};
      float kca[4] = {kc.x, kc.y, kc.z, kc.w};
      #pragma unroll
      for (int i = 0; i < 4; ++i)
        #pragma unroll
        for (int j = 0; j < 4; ++j) {
          s1[i][j] += qa[i]  * ka[j];    // q . k
          s3[i][j] += qca[i] * ka[j];    // qcnt . k      (max_sim, UNSCALED)
          s2[i][j] += qca[i] * kca[j];   // qcnt . kcnt
        }
    }

    float p1v[4][4], p2v[4][4], sc1[4], sc2[4];
    #pragma unroll
    for (int i = 0; i < 4; ++i) {
      float tmaxS = -INFINITY, tmaxC = -INFINITY, tminC = INFINITY, tmaxM = -INFINITY;
      #pragma unroll
      for (int j = 0; j < 4; ++j) {
        s1[i][j] *= 0.1875f;             // ATTN_MATRIX_SCALE * SCALE
        s2[i][j] *= 0.125f;              // SCALE
        tmaxS = fmaxf(tmaxS, s1[i][j]);
        tmaxC = fmaxf(tmaxC, s2[i][j]);
        tminC = fminf(tminC, s2[i][j]);
        tmaxM = fmaxf(tmaxM, s3[i][j]);
      }
      #pragma unroll
      for (int m = 1; m < 16; m <<= 1) {
        tmaxS = fmaxf(tmaxS, __shfl_xor(tmaxS, m));
        tmaxC = fmaxf(tmaxC, __shfl_xor(tmaxC, m));
        tminC = fminf(tminC, __shfl_xor(tminC, m));
        tmaxM = fmaxf(tmaxM, __shfl_xor(tmaxM, m));
      }
      mnCC[i] = fminf(mnCC[i], tminC);
      mxMS[i] = fmaxf(mxMS[i], tmaxM);
      float nM1 = fmaxf(M1[i], tmaxS);
      float nM2 = fmaxf(M2[i], tmaxC);
      sc1[i] = expf(M1[i] - nM1);
      sc2[i] = expf(M2[i] - nM2);
      float ps1 = 0.f, ps2 = 0.f;
      #pragma unroll
      for (int j = 0; j < 4; ++j) {
        p1v[i][j] = expf(s1[i][j] - nM1); ps1 += p1v[i][j];
        p2v[i][j] = expf(s2[i][j] - nM2); ps2 += p2v[i][j];
      }
      #pragma unroll
      for (int m = 1; m < 16; m <<= 1) {
        ps1 += __shfl_xor(ps1, m);
        ps2 += __shfl_xor(ps2, m);
      }
      S1[i] = S1[i] * sc1[i] + ps1;
      S2[i] = S2[i] * sc2[i] + ps2;
      M1[i] = nM1; M2[i] = nM2;
    }
    __syncthreads();  // (B) scores done reading KA/KB; prev PV done reading P

    // write P tiles ([j][r] so PV reads rows as float4)
    #pragma unroll
    for (int j = 0; j < 4; ++j) {
      float4 w1 = {p1v[0][j], p1v[1][j], p1v[2][j], p1v[3][j]};
      float4 w2 = {p2v[0][j], p2v[1][j], p2v[2][j], p2v[3][j]};
      *reinterpret_cast<float4*>(&P1[c0 + j][r0]) = w1;
      *reinterpret_cast<float4*>(&P2[c0 + j][r0]) = w2;
    }
    // stage V / Vcnt (natural [j][d]) into KA / KB
    for (int idx = tid; idx < 64 * 64; idx += 256) {
      int j = idx >> 6, d = idx & 63;
      KA[j][d] = vst[hbase + (size_t)(j0 + j) * DH + d];
      KB[j][d] = vct[hbase + (size_t)(j0 + j) * DH + d];
    }
    __syncthreads();  // (C) P and V ready

    #pragma unroll
    for (int i = 0; i < 4; ++i)
      #pragma unroll
      for (int j = 0; j < 4; ++j) { O1[i][j] *= sc1[i]; O2[i][j] *= sc2[i]; }

    #pragma unroll 8
    for (int j = 0; j < 64; ++j) {
      float4 a1 = *reinterpret_cast<const float4*>(&P1[j][r0]);
      float4 a2 = *reinterpret_cast<const float4*>(&P2[j][r0]);
      float4 b1 = *reinterpret_cast<const float4*>(&KA[j][c0]);
      float4 b2 = *reinterpret_cast<const float4*>(&KB[j][c0]);
      float pa1[4] = {a1.x, a1.y, a1.z, a1.w};
      float pa2[4] = {a2.x, a2.y, a2.z, a2.w};
      float vb1[4] = {b1.x, b1.y, b1.z, b1.w};
      float vb2[4] = {b2.x, b2.y, b2.z, b2.w};
      #pragma unroll
      for (int i = 0; i < 4; ++i)
        #pragma unroll
        for (int jj = 0; jj < 4; ++jj) {
          O1[i][jj] += pa1[i] * vb1[jj];
          O2[i][jj] += pa2[i] * vb2[jj];
        }
    }
    __syncthreads();  // (D) PV done before next tile's K stage overwrites
  }

  // epilogue: combine style/content halves with gvm
  #pragma unroll
  for (int i = 0; i < 4; ++i) {
    int n = n0 + r0 + i;
    float mv = mask[n];
    float m = (mv < 0.5f) ? 1.0f : (mv > 0.5f ? -1.0f : -mv);
    float gvm = (mnCC[i] - mxMS[i]) * m;
    float A1 = M1[i] + gvm, A2 = M2[i];
    float Mf = fmaxf(A1, A2);
    float w1 = expf(A1 - Mf), w2 = expf(A2 - Mf);
    float inv = 1.0f / (w1 * S1[i] + w2 * S2[i]);
    float4 o;
    o.x = (w1 * O1[i][0] + w2 * O2[i][0]) * inv;
    o.y = (w1 * O1[i][1] + w2 * O2[i][1]) * inv;
    o.z = (w1 * O1[i][2] + w2 * O2[i][2]) * inv;
    o.w = (w1 * O1[i][3] + w2 * O2[i][3]) * inv;
    *reinterpret_cast<float4*>(&mid[(size_t)n * INNER + h * DH + c0]) = o;
  }
}

// ---------------------------------------------------------------------------
// Kernel C: out = mid @ Wo + bo
// ---------------------------------------------------------------------------
__global__ __launch_bounds__(256) void gemm_out(
    const float* __restrict__ mid, const float* __restrict__ Wo,
    const float* __restrict__ bo, float* __restrict__ out)
{
  __shared__ float As[32][68];
  __shared__ float Bs[32][68];
  const int n0 = blockIdx.x * 64;
  const int o0 = blockIdx.y * 64;
  const int tid = threadIdx.x;
  const int ty = tid >> 4, tx = tid & 15;
  const int r0 = ty * 4, c0 = tx * 4;
  float acc[4][4] = {};
  for (int k0 = 0; k0 < INNER; k0 += 32) {
    for (int idx = tid; idx < 64 * 32; idx += 256) {
      int r = idx >> 5, kk = idx & 31;
      As[kk][r] = mid[(size_t)(n0 + r) * INNER + k0 + kk];
    }
    for (int idx = tid; idx < 32 * 64; idx += 256) {
      int kk = idx >> 6, c = idx & 63;
      Bs[kk][c] = Wo[(size_t)(k0 + kk) * QD + o0 + c];
    }
    __syncthreads();
    #pragma unroll
    for (int kk = 0; kk < 32; ++kk) {
      float4 a = *reinterpret_cast<const float4*>(&As[kk][r0]);
      float4 b = *reinterpret_cast<const float4*>(&Bs[kk][c0]);
      float av[4] = {a.x, a.y, a.z, a.w};
      float bv[4] = {b.x, b.y, b.z, b.w};
      #pragma unroll
      for (int i = 0; i < 4; ++i)
        #pragma unroll
        for (int j = 0; j < 4; ++j) acc[i][j] += av[i] * bv[j];
    }
    __syncthreads();
  }
  float4 bb = *reinterpret_cast<const float4*>(&bo[o0 + c0]);
  float bv[4] = {bb.x, bb.y, bb.z, bb.w};
  #pragma unroll
  for (int i = 0; i < 4; ++i) {
    int n = n0 + r0 + i;
    float4 o;
    o.x = acc[i][0] + bv[0];
    o.y = acc[i][1] + bv[1];
    o.z = acc[i][2] + bv[2];
    o.w = acc[i][3] + bv[3];
    *reinterpret_cast<float4*>(&out[(size_t)n * QD + o0 + c0]) = o;
  }
}

// ---------------------------------------------------------------------------
extern "C" void kernel_launch(void* const* d_in, const int* in_sizes, int n_in,
                              void* d_out, int out_size, void* d_ws, size_t ws_size,
                              hipStream_t stream) {
  const float* x    = (const float*)d_in[0];
  const float* Wq   = (const float*)d_in[1];
  const float* Wo   = (const float*)d_in[2];
  const float* bo   = (const float*)d_in[3];
  const float* qinj = (const float*)d_in[4];
  const float* kinj = (const float*)d_in[5];
  const float* vinj = (const float*)d_in[6];
  const float* kcnt = (const float*)d_in[7];
  const float* vcnt = (const float*)d_in[8];
  const float* mask = (const float*)d_in[9];
  float* out = (float*)d_out;

  float* qb  = (float*)d_ws;                       // [8][2304][64]
  float* mid = qb + (size_t)HEADS * NTOK * DH;     // [2304][512]

  gemm_qblend<<<dim3(NTILE, HEADS), 256, 0, stream>>>(x, Wq, qinj, qb);
  attn_fused <<<dim3(NTILE, HEADS), 256, 0, stream>>>(qb, kinj, vinj, qinj,
                                                      kcnt, vcnt, mask, mid);
  gemm_out   <<<dim3(NTILE, 5),     256, 0, stream>>>(mid, Wo, bo, out);
}

// Round 2
// 273.727 us; speedup vs baseline: 4.9708x; 4.9708x over previous
//
#include <hip/hip_runtime.h>
#include <math.h>

#define HEADS 8
#define NTOK  2304
#define DH    64
#define QD    320
#define INNER 512
#define NTILE 36   // NTOK / 64

typedef _Float16 f16;
typedef f16  f16x4 __attribute__((ext_vector_type(4)));
typedef f16  f16x8 __attribute__((ext_vector_type(8)));
typedef float f32x4 __attribute__((ext_vector_type(4)));

#define MFMA(a,b,c) __builtin_amdgcn_mfma_f32_16x16x32_f16((a),(b),(c),0,0,0)

// ---------------------------------------------------------------------------
// prep_cvt: qinj->qc16 (x1), kinj->k16 (x1), kcnt->kc16 (x0.125), fp32->fp16
// 3 tensors x 1179648 elems; 8 elems/thread; 442368 threads = 1728 blocks
// ---------------------------------------------------------------------------
__global__ __launch_bounds__(256) void prep_cvt(
    const float* __restrict__ qi, const float* __restrict__ ki,
    const float* __restrict__ kc,
    f16* __restrict__ oq, f16* __restrict__ ok, f16* __restrict__ okc)
{
  int i = blockIdx.x * 256 + threadIdx.x;          // 0..442367
  int seg = i / 147456;
  int off = i - seg * 147456;
  const float* src = (seg == 0) ? qi : (seg == 1) ? ki : kc;
  f16* dst = (seg == 0) ? oq : (seg == 1) ? ok : okc;
  float s = (seg == 2) ? 0.125f : 1.0f;
  float4 a = reinterpret_cast<const float4*>(src)[off * 2];
  float4 b = reinterpret_cast<const float4*>(src)[off * 2 + 1];
  f16x8 o;
  o[0] = (f16)(a.x * s); o[1] = (f16)(a.y * s);
  o[2] = (f16)(a.z * s); o[3] = (f16)(a.w * s);
  o[4] = (f16)(b.x * s); o[5] = (f16)(b.y * s);
  o[6] = (f16)(b.z * s); o[7] = (f16)(b.w * s);
  *reinterpret_cast<f16x8*>(&dst[(size_t)off * 8]) = o;
}

// ---------------------------------------------------------------------------
// prep_tr: v / v_cnt fp32 [h][n][d] -> fp16 transposed [h][d][n]
// ---------------------------------------------------------------------------
__global__ __launch_bounds__(256) void prep_tr(
    const float* __restrict__ v, const float* __restrict__ vc,
    f16* __restrict__ vt, f16* __restrict__ vct)
{
  __shared__ float T[64][65];
  const float* src = blockIdx.z ? vc : v;
  f16* dst = blockIdx.z ? vct : vt;
  const int h = blockIdx.y, n0 = blockIdx.x * 64;
  const int tid = threadIdx.x;
  const size_t base = ((size_t)h * NTOK + n0) * DH;
  for (int it = 0; it < 4; ++it) {
    int idx = tid + it * 256;                 // 0..1023 float4s
    int n = idx >> 4, d0 = (idx & 15) * 4;
    float4 a = *reinterpret_cast<const float4*>(&src[base + (size_t)n * DH + d0]);
    T[n][d0] = a.x; T[n][d0 + 1] = a.y; T[n][d0 + 2] = a.z; T[n][d0 + 3] = a.w;
  }
  __syncthreads();
  for (int it = 0; it < 2; ++it) {
    int idx = tid + it * 256;                 // 0..511 f16x8 outputs
    int d = idx >> 3, c0 = (idx & 7) * 8;
    f16x8 o;
    #pragma unroll
    for (int i = 0; i < 8; ++i) o[i] = (f16)T[c0 + i][d];
    *reinterpret_cast<f16x8*>(&dst[(size_t)(h * 64 + d) * NTOK + n0 + c0]) = o;
  }
}

// ---------------------------------------------------------------------------
// gemm_qblend: qhat[h][n][d] = 0.09375*(qinj + x@Wq)   (fp16 out, scale folded:
//   0.5 blend * 0.1875 attn scale = 0.09375)
// ---------------------------------------------------------------------------
__global__ __launch_bounds__(256) void gemm_qblend(
    const float* __restrict__ x, const float* __restrict__ Wq,
    const float* __restrict__ qinj, f16* __restrict__ qhat)
{
  __shared__ float As[32][68];
  __shared__ float Bs[32][68];
  const int n0 = blockIdx.x * 64;
  const int h  = blockIdx.y;
  const int o0 = h * 64;
  const int tid = threadIdx.x;
  const int ty = tid >> 4, tx = tid & 15;
  const int r0 = ty * 4, c0 = tx * 4;
  float acc[4][4] = {};
  for (int k0 = 0; k0 < QD; k0 += 32) {
    for (int idx = tid; idx < 64 * 32; idx += 256) {
      int r = idx >> 5, kk = idx & 31;
      As[kk][r] = x[(size_t)(n0 + r) * QD + k0 + kk];
    }
    for (int idx = tid; idx < 32 * 64; idx += 256) {
      int kk = idx >> 6, c = idx & 63;
      Bs[kk][c] = Wq[(size_t)(k0 + kk) * INNER + o0 + c];
    }
    __syncthreads();
    #pragma unroll
    for (int kk = 0; kk < 32; ++kk) {
      float4 a = *reinterpret_cast<const float4*>(&As[kk][r0]);
      float4 b = *reinterpret_cast<const float4*>(&Bs[kk][c0]);
      float av[4] = {a.x, a.y, a.z, a.w};
      float bv[4] = {b.x, b.y, b.z, b.w};
      #pragma unroll
      for (int i = 0; i < 4; ++i)
        #pragma unroll
        for (int j = 0; j < 4; ++j) acc[i][j] += av[i] * bv[j];
    }
    __syncthreads();
  }
  #pragma unroll
  for (int i = 0; i < 4; ++i) {
    int n = n0 + r0 + i;
    size_t base = ((size_t)h * NTOK + n) * DH + c0;
    float4 qi = *reinterpret_cast<const float4*>(&qinj[base]);
    f16x4 o;
    o[0] = (f16)(0.09375f * (qi.x + acc[i][0]));
    o[1] = (f16)(0.09375f * (qi.y + acc[i][1]));
    o[2] = (f16)(0.09375f * (qi.z + acc[i][2]));
    o[3] = (f16)(0.09375f * (qi.w + acc[i][3]));
    *reinterpret_cast<f16x4*>(&qhat[base]) = o;
  }
}

// ---------------------------------------------------------------------------
// attn_mfma: fused 3-sim + gvm + concat online softmax + 2xPV, all MFMA fp16.
// grid 288 (1D); h = bid&7 (XCD-pinned), qt = bid>>3. 4 waves; wave w owns
// q rows [n0+16w, n0+16w+16). 16x16x32 f16 MFMA; C layout col=l&15,
// row=(l>>4)*4+reg (m89-verified).
// ---------------------------------------------------------------------------
__global__ __launch_bounds__(256, 2) void attn_mfma(
    const f16* __restrict__ qhat, const f16* __restrict__ qc16,
    const f16* __restrict__ k16,  const f16* __restrict__ kc16,
    const f16* __restrict__ vt16, const f16* __restrict__ vct16,
    const float* __restrict__ mask, f16* __restrict__ mid)
{
  __shared__ f16 Ksh [64][72];
  __shared__ f16 KCsh[64][72];
  __shared__ f16 VTsh[64][72];   // [d][j]
  __shared__ f16 VCTsh[64][72];  // [d][j]
  __shared__ f16 P1sh[64][72];   // [q_local][j]
  __shared__ f16 P2sh[64][72];

  const int bid = blockIdx.x;
  const int h  = bid & 7;        // 36 blocks of head h land on one XCD
  const int qt = bid >> 3;
  const int n0 = qt * 64;
  const int tid = threadIdx.x;
  const int w = tid >> 6, l = tid & 63;
  const int lq = l & 15, lk = l >> 4;
  const size_t hb = (size_t)h * NTOK * DH;

  // Q fragments straight from global (16B/lane, contiguous)
  f16x8 qhf[2], qcf[2];
  {
    const size_t qrow = hb + (size_t)(n0 + 16 * w + lq) * DH;
    #pragma unroll
    for (int ks = 0; ks < 2; ++ks) {
      qhf[ks] = *reinterpret_cast<const f16x8*>(&qhat[qrow + ks * 32 + lk * 8]);
      qcf[ks] = *reinterpret_cast<const f16x8*>(&qc16[qrow + ks * 32 + lk * 8]);
    }
  }

  f32x4 O1[4] = {}, O2[4] = {};
  float M1[4], S1[4] = {}, M2[4], S2[4] = {};
  float mnCC[4], mxMS[4];
  #pragma unroll
  for (int r = 0; r < 4; ++r) {
    M1[r] = -INFINITY; M2[r] = -INFINITY;
    mnCC[r] = INFINITY; mxMS[r] = -INFINITY;
  }

  const f16* gVTb  = vt16  + (size_t)h * DH * NTOK;
  const f16* gVCTb = vct16 + (size_t)h * DH * NTOK;

  for (int jt = 0; jt < NTILE; ++jt) {
    const int j0 = jt * 64;
    __syncthreads();  // prev PV done reading P/VT; prev QK done reading K
    // ---- stage K, KC ([j][d]) and VT, VCT ([d][j]) as 16B copies ----
    {
      const int4* gK  = reinterpret_cast<const int4*>(k16  + hb + (size_t)j0 * DH);
      const int4* gKC = reinterpret_cast<const int4*>(kc16 + hb + (size_t)j0 * DH);
      #pragma unroll
      for (int it = 0; it < 2; ++it) {
        int idx = tid + it * 256;           // 0..511
        int j = idx >> 3, dc = (idx & 7) * 8;
        *reinterpret_cast<int4*>(&Ksh [j][dc]) = gK [idx];
        *reinterpret_cast<int4*>(&KCsh[j][dc]) = gKC[idx];
        int d = idx >> 3, jc = (idx & 7) * 8;
        *reinterpret_cast<int4*>(&VTsh[d][jc]) =
            *reinterpret_cast<const int4*>(gVTb  + (size_t)d * NTOK + j0 + jc);
        *reinterpret_cast<int4*>(&VCTsh[d][jc]) =
            *reinterpret_cast<const int4*>(gVCTb + (size_t)d * NTOK + j0 + jc);
      }
    }
    __syncthreads();

    // ---- QK^T: 3 sims ----
    f32x4 s1[4] = {}, s2[4] = {}, s3[4] = {};
    #pragma unroll
    for (int ks = 0; ks < 2; ++ks) {
      #pragma unroll
      for (int jf = 0; jf < 4; ++jf) {
        f16x8 bk = *reinterpret_cast<const f16x8*>(&Ksh [jf * 16 + lq][ks * 32 + lk * 8]);
        f16x8 bc = *reinterpret_cast<const f16x8*>(&KCsh[jf * 16 + lq][ks * 32 + lk * 8]);
        s1[jf] = MFMA(qhf[ks], bk, s1[jf]);   // sim      (scales folded in qhat)
        s3[jf] = MFMA(qcf[ks], bk, s3[jf]);   // max_sim  (unscaled)
        s2[jf] = MFMA(qcf[ks], bc, s2[jf]);   // cc_sim   (0.125 folded in kc16)
      }
    }

    // ---- online softmax (row = lk*4+r, cols = 16 lanes sharing lk) ----
    float sc1[4], sc2[4];
    #pragma unroll
    for (int r = 0; r < 4; ++r) {
      float mS = fmaxf(fmaxf(s1[0][r], s1[1][r]), fmaxf(s1[2][r], s1[3][r]));
      float mC = fmaxf(fmaxf(s2[0][r], s2[1][r]), fmaxf(s2[2][r], s2[3][r]));
      float nC = fminf(fminf(s2[0][r], s2[1][r]), fminf(s2[2][r], s2[3][r]));
      float mM = fmaxf(fmaxf(s3[0][r], s3[1][r]), fmaxf(s3[2][r], s3[3][r]));
      #pragma unroll
      for (int m = 1; m < 16; m <<= 1) {
        mS = fmaxf(mS, __shfl_xor(mS, m));
        mC = fmaxf(mC, __shfl_xor(mC, m));
        nC = fminf(nC, __shfl_xor(nC, m));
        mM = fmaxf(mM, __shfl_xor(mM, m));
      }
      mnCC[r] = fminf(mnCC[r], nC);
      mxMS[r] = fmaxf(mxMS[r], mM);
      float nM1 = fmaxf(M1[r], mS);
      float nM2 = fmaxf(M2[r], mC);
      sc1[r] = __expf(M1[r] - nM1);
      sc2[r] = __expf(M2[r] - nM2);
      M1[r] = nM1; M2[r] = nM2;
      float ps1 = 0.f, ps2 = 0.f;
      #pragma unroll
      for (int jf = 0; jf < 4; ++jf) {
        float p1 = __expf(s1[jf][r] - nM1); s1[jf][r] = p1; ps1 += p1;
        float p2 = __expf(s2[jf][r] - nM2); s2[jf][r] = p2; ps2 += p2;
      }
      #pragma unroll
      for (int m = 1; m < 16; m <<= 1) {
        ps1 += __shfl_xor(ps1, m);
        ps2 += __shfl_xor(ps2, m);
      }
      S1[r] = S1[r] * sc1[r] + ps1;
      S2[r] = S2[r] * sc2[r] + ps2;
    }

    // ---- write P (fp16) ----
    #pragma unroll
    for (int jf = 0; jf < 4; ++jf)
      #pragma unroll
      for (int r = 0; r < 4; ++r) {
        P1sh[16 * w + lk * 4 + r][jf * 16 + lq] = (f16)s1[jf][r];
        P2sh[16 * w + lk * 4 + r][jf * 16 + lq] = (f16)s2[jf][r];
      }
    __syncthreads();

    // ---- rescale O, then PV ----
    #pragma unroll
    for (int df = 0; df < 4; ++df)
      #pragma unroll
      for (int r = 0; r < 4; ++r) {
        O1[df][r] *= sc1[r];
        O2[df][r] *= sc2[r];
      }
    #pragma unroll
    for (int js = 0; js < 2; ++js) {
      f16x8 pa1 = *reinterpret_cast<const f16x8*>(&P1sh[16 * w + lq][js * 32 + lk * 8]);
      f16x8 pa2 = *reinterpret_cast<const f16x8*>(&P2sh[16 * w + lq][js * 32 + lk * 8]);
      #pragma unroll
      for (int df = 0; df < 4; ++df) {
        f16x8 vb  = *reinterpret_cast<const f16x8*>(&VTsh [df * 16 + lq][js * 32 + lk * 8]);
        f16x8 vcb = *reinterpret_cast<const f16x8*>(&VCTsh[df * 16 + lq][js * 32 + lk * 8]);
        O1[df] = MFMA(pa1, vb,  O1[df]);
        O2[df] = MFMA(pa2, vcb, O2[df]);
      }
    }
  }

  // ---- epilogue: combine halves with gvm ----
  #pragma unroll
  for (int r = 0; r < 4; ++r) {
    int n = n0 + 16 * w + lk * 4 + r;
    float mv = mask[n];
    float mm = (mv < 0.5f) ? 1.0f : (mv > 0.5f ? -1.0f : -mv);
    float gvm = (mnCC[r] - mxMS[r]) * mm;
    float A1 = M1[r] + gvm, A2 = M2[r];
    float Mf = fmaxf(A1, A2);
    float w1 = __expf(A1 - Mf), w2 = __expf(A2 - Mf);
    float inv = 1.0f / (w1 * S1[r] + w2 * S2[r]);
    #pragma unroll
    for (int df = 0; df < 4; ++df) {
      float val = (w1 * O1[df][r] + w2 * O2[df][r]) * inv;
      mid[(size_t)n * INNER + h * DH + df * 16 + lq] = (f16)val;
    }
  }
}

// ---------------------------------------------------------------------------
// gemm_out: out = mid(f16) @ Wo + bo   (fp32 accumulate)
// ---------------------------------------------------------------------------
__global__ __launch_bounds__(256) void gemm_out(
    const f16* __restrict__ mid, const float* __restrict__ Wo,
    const float* __restrict__ bo, float* __restrict__ out)
{
  __shared__ float As[32][68];
  __shared__ float Bs[32][68];
  const int n0 = blockIdx.x * 64;
  const int o0 = blockIdx.y * 64;
  const int tid = threadIdx.x;
  const int ty = tid >> 4, tx = tid & 15;
  const int r0 = ty * 4, c0 = tx * 4;
  float acc[4][4] = {};
  for (int k0 = 0; k0 < INNER; k0 += 32) {
    for (int idx = tid; idx < 64 * 16; idx += 256) {
      int r = idx >> 4, k2 = (idx & 15) * 2;
      unsigned u = *reinterpret_cast<const unsigned*>(
          &mid[(size_t)(n0 + r) * INNER + k0 + k2]);
      f16 lo = reinterpret_cast<const f16*>(&u)[0];
      f16 hi = reinterpret_cast<const f16*>(&u)[1];
      As[k2][r] = (float)lo;
      As[k2 + 1][r] = (float)hi;
    }
    for (int idx = tid; idx < 32 * 64; idx += 256) {
      int kk = idx >> 6, c = idx & 63;
      Bs[kk][c] = Wo[(size_t)(k0 + kk) * QD + o0 + c];
    }
    __syncthreads();
    #pragma unroll
    for (int kk = 0; kk < 32; ++kk) {
      float4 a = *reinterpret_cast<const float4*>(&As[kk][r0]);
      float4 b = *reinterpret_cast<const float4*>(&Bs[kk][c0]);
      float av[4] = {a.x, a.y, a.z, a.w};
      float bv[4] = {b.x, b.y, b.z, b.w};
      #pragma unroll
      for (int i = 0; i < 4; ++i)
        #pragma unroll
        for (int j = 0; j < 4; ++j) acc[i][j] += av[i] * bv[j];
    }
    __syncthreads();
  }
  float4 bb = *reinterpret_cast<const float4*>(&bo[o0 + c0]);
  float bv[4] = {bb.x, bb.y, bb.z, bb.w};
  #pragma unroll
  for (int i = 0; i < 4; ++i) {
    int n = n0 + r0 + i;
    float4 o;
    o.x = acc[i][0] + bv[0];
    o.y = acc[i][1] + bv[1];
    o.z = acc[i][2] + bv[2];
    o.w = acc[i][3] + bv[3];
    *reinterpret_cast<float4*>(&out[(size_t)n * QD + o0 + c0]) = o;
  }
}

// ---------------------------------------------------------------------------
extern "C" void kernel_launch(void* const* d_in, const int* in_sizes, int n_in,
                              void* d_out, int out_size, void* d_ws, size_t ws_size,
                              hipStream_t stream) {
  const float* x    = (const float*)d_in[0];
  const float* Wq   = (const float*)d_in[1];
  const float* Wo   = (const float*)d_in[2];
  const float* bo   = (const float*)d_in[3];
  const float* qinj = (const float*)d_in[4];
  const float* kinj = (const float*)d_in[5];
  const float* vinj = (const float*)d_in[6];
  const float* kcnt = (const float*)d_in[7];
  const float* vcnt = (const float*)d_in[8];
  const float* mask = (const float*)d_in[9];
  float* out = (float*)d_out;

  const size_t T = (size_t)HEADS * NTOK * DH;   // 1179648
  f16* qhat = (f16*)d_ws;
  f16* qc16 = qhat + T;
  f16* k16  = qc16 + T;
  f16* kc16 = k16  + T;
  f16* vt16 = kc16 + T;
  f16* vct16= vt16 + T;
  f16* mid  = vct16 + T;                        // [2304][512] f16

  prep_cvt   <<<1728, 256, 0, stream>>>(qinj, kinj, kcnt, qc16, k16, kc16);
  prep_tr    <<<dim3(NTILE, HEADS, 2), 256, 0, stream>>>(vinj, vcnt, vt16, vct16);
  gemm_qblend<<<dim3(NTILE, HEADS), 256, 0, stream>>>(x, Wq, qinj, qhat);
  attn_mfma  <<<NTILE * HEADS, 256, 0, stream>>>(qhat, qc16, k16, kc16,
                                                 vt16, vct16, mask, mid);
  gemm_out   <<<dim3(NTILE, 5), 256, 0, stream>>>(mid, Wo, bo, out);
}

// Round 3
// 255.182 us; speedup vs baseline: 5.3321x; 1.0727x over previous
//
#include <hip/hip_runtime.h>
#include <math.h>

#define HEADS 8
#define NTOK  2304
#define DH    64
#define QD    320
#define INNER 512

typedef _Float16 f16;
typedef f16  f16x4 __attribute__((ext_vector_type(4)));
typedef f16  f16x8 __attribute__((ext_vector_type(8)));
typedef float f32x4 __attribute__((ext_vector_type(4)));

#define MFMA(a,b,c) __builtin_amdgcn_mfma_f32_16x16x32_f16((a),(b),(c),0,0,0)

// ---------------------------------------------------------------------------
// prep_cvt: fp32->f16 flat converts: qinj->qc16(x1), kinj->k16(x1),
// kcnt->kc16(x0.125), x->x16(x1). 534528 x8-chunks = 2088 blocks.
// ---------------------------------------------------------------------------
__global__ __launch_bounds__(256) void prep_cvt(
    const float* __restrict__ qi, const float* __restrict__ ki,
    const float* __restrict__ kc, const float* __restrict__ x,
    f16* __restrict__ oq, f16* __restrict__ ok, f16* __restrict__ okc,
    f16* __restrict__ ox)
{
  int i = blockIdx.x * 256 + threadIdx.x;
  const float* src; f16* dst; float s = 1.0f; int off;
  if (i < 147456)      { src = qi; dst = oq;  off = i; }
  else if (i < 294912) { src = ki; dst = ok;  off = i - 147456; }
  else if (i < 442368) { src = kc; dst = okc; off = i - 294912; s = 0.125f; }
  else                 { src = x;  dst = ox;  off = i - 442368; }
  float4 a = reinterpret_cast<const float4*>(src)[off * 2];
  float4 b = reinterpret_cast<const float4*>(src)[off * 2 + 1];
  f16x8 o;
  o[0] = (f16)(a.x * s); o[1] = (f16)(a.y * s);
  o[2] = (f16)(a.z * s); o[3] = (f16)(a.w * s);
  o[4] = (f16)(b.x * s); o[5] = (f16)(b.y * s);
  o[6] = (f16)(b.z * s); o[7] = (f16)(b.w * s);
  *reinterpret_cast<f16x8*>(&dst[(size_t)off * 8]) = o;
}

// ---------------------------------------------------------------------------
// prep_tr: v / v_cnt fp32 [h][n][d] -> fp16 transposed [h][d][n]
// ---------------------------------------------------------------------------
__global__ __launch_bounds__(256) void prep_tr(
    const float* __restrict__ v, const float* __restrict__ vc,
    f16* __restrict__ vt, f16* __restrict__ vct)
{
  __shared__ float T[64][65];
  const float* src = blockIdx.z ? vc : v;
  f16* dst = blockIdx.z ? vct : vt;
  const int h = blockIdx.y, n0 = blockIdx.x * 64;
  const int tid = threadIdx.x;
  const size_t base = ((size_t)h * NTOK + n0) * DH;
  for (int it = 0; it < 4; ++it) {
    int idx = tid + it * 256;
    int n = idx >> 4, d0 = (idx & 15) * 4;
    float4 a = *reinterpret_cast<const float4*>(&src[base + (size_t)n * DH + d0]);
    T[n][d0] = a.x; T[n][d0 + 1] = a.y; T[n][d0 + 2] = a.z; T[n][d0 + 3] = a.w;
  }
  __syncthreads();
  for (int it = 0; it < 2; ++it) {
    int idx = tid + it * 256;
    int d = idx >> 3, c0 = (idx & 7) * 8;
    f16x8 o;
    #pragma unroll
    for (int i = 0; i < 8; ++i) o[i] = (f16)T[c0 + i][d];
    *reinterpret_cast<f16x8*>(&dst[(size_t)(h * 64 + d) * NTOK + n0 + c0]) = o;
  }
}

// ---------------------------------------------------------------------------
// prep_trW: Wq [320][512] -> WqT f16 [512][320]; Wo [512][320] -> WoT [320][512]
// grid (40, 2): exact 64x64 tiles.
// ---------------------------------------------------------------------------
__global__ __launch_bounds__(256) void prep_trW(
    const float* __restrict__ Wq, const float* __restrict__ Wo,
    f16* __restrict__ WqT, f16* __restrict__ WoT)
{
  __shared__ float T[64][65];
  const int z = blockIdx.y;
  const float* src = z ? Wo : Wq;
  f16* dst = z ? WoT : WqT;
  const int R = z ? INNER : QD;
  const int C = z ? QD : INNER;
  const int ctiles = C >> 6;
  const int rt = blockIdx.x / ctiles, ct = blockIdx.x % ctiles;
  const int tid = threadIdx.x;
  for (int it = 0; it < 4; ++it) {
    int idx = tid + it * 256;
    int r = idx >> 4, c4 = (idx & 15) * 4;
    float4 a = *reinterpret_cast<const float4*>(&src[(size_t)(rt * 64 + r) * C + ct * 64 + c4]);
    T[r][c4] = a.x; T[r][c4 + 1] = a.y; T[r][c4 + 2] = a.z; T[r][c4 + 3] = a.w;
  }
  __syncthreads();
  for (int it = 0; it < 4; ++it) {
    int idx = tid + it * 256;
    int c = idx >> 4, r4 = (idx & 15) * 4;
    f16x4 o;
    #pragma unroll
    for (int i = 0; i < 4; ++i) o[i] = (f16)T[r4 + i][c];
    *reinterpret_cast<f16x4*>(&dst[(size_t)(ct * 64 + c) * R + rt * 64 + r4]) = o;
  }
}

// ---------------------------------------------------------------------------
// qblend_mfma: qhat[h][n][d] = 0.09375*(qinj + x@Wq), f16 out, MFMA.
// grid (72, 8); 4 waves: w&1 = q-sub(16 rows), w>>1 = col-half(32).
// ---------------------------------------------------------------------------
__global__ __launch_bounds__(256) void qblend_mfma(
    const f16* __restrict__ x16, const f16* __restrict__ WqT,
    const float* __restrict__ qinj, f16* __restrict__ qhat)
{
  const int qt = blockIdx.x, h = blockIdx.y;
  const int n0 = qt * 32;
  const int tid = threadIdx.x;
  const int w = tid >> 6, l = tid & 63, lq = l & 15, lk = l >> 4;
  const int qsub = w & 1, ch = w >> 1;
  f32x4 acc[2] = {};
  const f16* arow = x16 + (size_t)(n0 + qsub * 16 + lq) * QD;
  #pragma unroll
  for (int ks = 0; ks < 10; ++ks) {
    f16x8 a = *reinterpret_cast<const f16x8*>(&arow[ks * 32 + lk * 8]);
    #pragma unroll
    for (int df = 0; df < 2; ++df) {
      const f16* brow = WqT + (size_t)(h * 64 + ch * 32 + df * 16 + lq) * QD;
      f16x8 b = *reinterpret_cast<const f16x8*>(&brow[ks * 32 + lk * 8]);
      acc[df] = MFMA(a, b, acc[df]);
    }
  }
  #pragma unroll
  for (int df = 0; df < 2; ++df)
    #pragma unroll
    for (int r = 0; r < 4; ++r) {
      int n = n0 + qsub * 16 + lk * 4 + r;
      int d = ch * 32 + df * 16 + lq;
      size_t idx = ((size_t)h * NTOK + n) * DH + d;
      qhat[idx] = (f16)(0.09375f * (qinj[idx] + acc[df][r]));
    }
}

// ---------------------------------------------------------------------------
// attn2: swapped-MFMA fused attention with KV-split x4.
// grid 1152: h = bid&7 (XCD-pinned), qt = bid>>3 (16 q-rows).
// 4 waves; wave w does key tiles [w*9, w*9+9). In-lane softmax (q = lane&15).
// LDS: K/KC staged [64][72]; P per-wave [16][72]x2; merge aliased at end.
// ---------------------------------------------------------------------------
__global__ __launch_bounds__(256, 4) void attn2(
    const f16* __restrict__ qhat, const f16* __restrict__ qc16,
    const f16* __restrict__ k16,  const f16* __restrict__ kc16,
    const f16* __restrict__ vt16, const f16* __restrict__ vct16,
    const float* __restrict__ mask, f16* __restrict__ mid)
{
  __shared__ __align__(16) unsigned char smem[36864];
  f16 (*Ksh)[72]  = reinterpret_cast<f16(*)[72]>(smem);
  f16 (*KCsh)[72] = reinterpret_cast<f16(*)[72]>(smem + 9216);

  const int bid = blockIdx.x;
  const int h = bid & 7, qt = bid >> 3;
  const int n0 = qt * 16;
  const int tid = threadIdx.x;
  const int w = tid >> 6, l = tid & 63;
  const int lq = l & 15, lk = l >> 4;
  const size_t hb = (size_t)h * NTOK * DH;
  f16* P1 = reinterpret_cast<f16*>(smem + 18432 + w * 4608);  // [16][72]
  f16* P2 = P1 + 16 * 72;

  const int nrow = n0 + lq;           // this lane's q-row
  f16x8 qB[2], qcB[2];
  {
    const size_t qr = hb + (size_t)nrow * DH;
    #pragma unroll
    for (int ks = 0; ks < 2; ++ks) {
      qB [ks] = *reinterpret_cast<const f16x8*>(&qhat[qr + ks * 32 + lk * 8]);
      qcB[ks] = *reinterpret_cast<const f16x8*>(&qc16[qr + ks * 32 + lk * 8]);
    }
  }
  const f16* vb1[4]; const f16* vb2[4];
  #pragma unroll
  for (int df = 0; df < 4; ++df) {
    vb1[df] = vt16  + (size_t)(h * DH + df * 16 + lq) * NTOK;
    vb2[df] = vct16 + (size_t)(h * DH + df * 16 + lq) * NTOK;
  }

  float M1 = -INFINITY, S1 = 0.f, M2 = -INFINITY, S2 = 0.f;
  float mn = INFINITY, mx = -INFINITY;
  f32x4 O1[4] = {}, O2[4] = {};

  for (int t = 0; t < 9; ++t) {
    const int j0 = (w * 9 + t) * 64;
    __syncthreads();   // all waves done reading Ksh/KCsh of prev iter
    {
      const int4* gK  = reinterpret_cast<const int4*>(k16  + hb + (size_t)j0 * DH);
      const int4* gKC = reinterpret_cast<const int4*>(kc16 + hb + (size_t)j0 * DH);
      #pragma unroll
      for (int it = 0; it < 2; ++it) {
        int idx = tid + it * 256;          // 0..511 per tensor
        int key = idx >> 3, c = idx & 7;
        *reinterpret_cast<int4*>(&Ksh [key][c * 8]) = gK [idx];
        *reinterpret_cast<int4*>(&KCsh[key][c * 8]) = gKC[idx];
      }
    }
    __syncthreads();
    // -- wait: each wave needs ITS tile; all waves staged different j0!  --
    // (staging above loads this block's per-wave tiles? NO -- j0 is per-wave.)
    // Correctness: staging used per-wave j0 in global but shared dest ->
    // 4 waves wrote overlapping dest. FIX: per-wave private K region instead.
    // (see below -- this path is not used; kept unreachable)
    break;
  }

  // ======== actual loop (per-wave private K staging in registers) ========
  // Each wave loads its own K/KC fragments directly from global (L2-resident),
  // avoiding the shared-dest conflict entirely. A-frag: 16B contiguous.
  M1 = -INFINITY; S1 = 0.f; M2 = -INFINITY; S2 = 0.f;
  mn = INFINITY; mx = -INFINITY;
  #pragma unroll
  for (int df = 0; df < 4; ++df) { O1[df] = (f32x4){0,0,0,0}; O2[df] = (f32x4){0,0,0,0}; }

  for (int t = 0; t < 9; ++t) {
    const int j0 = (w * 9 + t) * 64;
    // ---- QK^T (swapped): s[key][q] ----
    f32x4 s1[4] = {}, s2[4] = {}, s3[4] = {};
    #pragma unroll
    for (int ks = 0; ks < 2; ++ks) {
      #pragma unroll
      for (int jf = 0; jf < 4; ++jf) {
        const size_t krow = hb + (size_t)(j0 + jf * 16 + lq) * DH + ks * 32 + lk * 8;
        f16x8 aK  = *reinterpret_cast<const f16x8*>(&k16 [krow]);
        f16x8 aKC = *reinterpret_cast<const f16x8*>(&kc16[krow]);
        s1[jf] = MFMA(aK,  qB [ks], s1[jf]);
        s3[jf] = MFMA(aK,  qcB[ks], s3[jf]);
        s2[jf] = MFMA(aKC, qcB[ks], s2[jf]);
      }
    }
    // ---- in-lane reductions over 16 keys + 2 shfls across lk-groups ----
    float mS, mC, nC, mM;
    {
      float a0, a1, a2, a3;
      a0 = fmaxf(fmaxf(s1[0][0], s1[0][1]), fmaxf(s1[0][2], s1[0][3]));
      a1 = fmaxf(fmaxf(s1[1][0], s1[1][1]), fmaxf(s1[1][2], s1[1][3]));
      a2 = fmaxf(fmaxf(s1[2][0], s1[2][1]), fmaxf(s1[2][2], s1[2][3]));
      a3 = fmaxf(fmaxf(s1[3][0], s1[3][1]), fmaxf(s1[3][2], s1[3][3]));
      mS = fmaxf(fmaxf(a0, a1), fmaxf(a2, a3));
      a0 = fmaxf(fmaxf(s2[0][0], s2[0][1]), fmaxf(s2[0][2], s2[0][3]));
      a1 = fmaxf(fmaxf(s2[1][0], s2[1][1]), fmaxf(s2[1][2], s2[1][3]));
      a2 = fmaxf(fmaxf(s2[2][0], s2[2][1]), fmaxf(s2[2][2], s2[2][3]));
      a3 = fmaxf(fmaxf(s2[3][0], s2[3][1]), fmaxf(s2[3][2], s2[3][3]));
      mC = fmaxf(fmaxf(a0, a1), fmaxf(a2, a3));
      a0 = fminf(fminf(s2[0][0], s2[0][1]), fminf(s2[0][2], s2[0][3]));
      a1 = fminf(fminf(s2[1][0], s2[1][1]), fminf(s2[1][2], s2[1][3]));
      a2 = fminf(fminf(s2[2][0], s2[2][1]), fminf(s2[2][2], s2[2][3]));
      a3 = fminf(fminf(s2[3][0], s2[3][1]), fminf(s2[3][2], s2[3][3]));
      nC = fminf(fminf(a0, a1), fminf(a2, a3));
      a0 = fmaxf(fmaxf(s3[0][0], s3[0][1]), fmaxf(s3[0][2], s3[0][3]));
      a1 = fmaxf(fmaxf(s3[1][0], s3[1][1]), fmaxf(s3[1][2], s3[1][3]));
      a2 = fmaxf(fmaxf(s3[2][0], s3[2][1]), fmaxf(s3[2][2], s3[2][3]));
      a3 = fmaxf(fmaxf(s3[3][0], s3[3][1]), fmaxf(s3[3][2], s3[3][3]));
      mM = fmaxf(fmaxf(a0, a1), fmaxf(a2, a3));
    }
    mS = fmaxf(mS, __shfl_xor(mS, 16)); mS = fmaxf(mS, __shfl_xor(mS, 32));
    mC = fmaxf(mC, __shfl_xor(mC, 16)); mC = fmaxf(mC, __shfl_xor(mC, 32));
    nC = fminf(nC, __shfl_xor(nC, 16)); nC = fminf(nC, __shfl_xor(nC, 32));
    mM = fmaxf(mM, __shfl_xor(mM, 16)); mM = fmaxf(mM, __shfl_xor(mM, 32));
    mn = fminf(mn, nC);
    mx = fmaxf(mx, mM);
    float nM1 = fmaxf(M1, mS), nM2 = fmaxf(M2, mC);
    float sc1 = __expf(M1 - nM1), sc2 = __expf(M2 - nM2);
    M1 = nM1; M2 = nM2;
    float ps1 = 0.f, ps2 = 0.f;
    #pragma unroll
    for (int jf = 0; jf < 4; ++jf) {
      #pragma unroll
      for (int r = 0; r < 4; ++r) {
        float p1 = __expf(s1[jf][r] - nM1); s1[jf][r] = p1;
        float p2 = __expf(s2[jf][r] - nM2); s2[jf][r] = p2;
      }
      ps1 += (s1[jf][0] + s1[jf][1]) + (s1[jf][2] + s1[jf][3]);
      ps2 += (s2[jf][0] + s2[jf][1]) + (s2[jf][2] + s2[jf][3]);
    }
    ps1 += __shfl_xor(ps1, 16); ps1 += __shfl_xor(ps1, 32);
    ps2 += __shfl_xor(ps2, 16); ps2 += __shfl_xor(ps2, 32);
    S1 = S1 * sc1 + ps1;
    S2 = S2 * sc2 + ps2;
    // ---- write P (wave-private LDS, no barrier) ----
    #pragma unroll
    for (int jf = 0; jf < 4; ++jf)
      #pragma unroll
      for (int r = 0; r < 4; ++r) {
        P1[lq * 72 + jf * 16 + lk * 4 + r] = (f16)s1[jf][r];
        P2[lq * 72 + jf * 16 + lk * 4 + r] = (f16)s2[jf][r];
      }
    // ---- rescale O ----
    #pragma unroll
    for (int df = 0; df < 4; ++df) { O1[df] *= sc1; O2[df] *= sc2; }
    // ---- PV (swapped): O[d][q] ----
    #pragma unroll
    for (int ks = 0; ks < 2; ++ks) {
      f16x8 pB1 = *reinterpret_cast<const f16x8*>(&P1[lq * 72 + ks * 32 + lk * 8]);
      f16x8 pB2 = *reinterpret_cast<const f16x8*>(&P2[lq * 72 + ks * 32 + lk * 8]);
      #pragma unroll
      for (int df = 0; df < 4; ++df) {
        f16x8 aV  = *reinterpret_cast<const f16x8*>(&vb1[df][j0 + ks * 32 + lk * 8]);
        f16x8 aVC = *reinterpret_cast<const f16x8*>(&vb2[df][j0 + ks * 32 + lk * 8]);
        O1[df] = MFMA(aV,  pB1, O1[df]);
        O2[df] = MFMA(aVC, pB2, O2[df]);
      }
    }
  }

  // ---- merge 4 KV-quarters (LDS aliased over K/P regions, all dead) ----
  float* mF = reinterpret_cast<float*>(smem);           // [3][64][6]
  float* mO = reinterpret_cast<float*>(smem + 4608);    // [3][64][32]
  __syncthreads();
  if (w > 0) {
    float* f = mF + ((w - 1) * 64 + l) * 6;
    f[0] = M1; f[1] = S1; f[2] = M2; f[3] = S2; f[4] = mn; f[5] = mx;
    float* o = mO + ((w - 1) * 64 + l) * 32;
    #pragma unroll
    for (int df = 0; df < 4; ++df)
      #pragma unroll
      for (int r = 0; r < 4; ++r) {
        o[df * 4 + r]      = O1[df][r];
        o[16 + df * 4 + r] = O2[df][r];
      }
  }
  __syncthreads();
  if (w == 0) {
    #pragma unroll
    for (int p = 0; p < 3; ++p) {
      const float* f = mF + (p * 64 + l) * 6;
      const float* o = mO + (p * 64 + l) * 32;
      float bM1 = f[0], bS1 = f[1], bM2 = f[2], bS2 = f[3];
      mn = fminf(mn, f[4]); mx = fmaxf(mx, f[5]);
      float nM1 = fmaxf(M1, bM1);
      float e1a = __expf(M1 - nM1), e1b = __expf(bM1 - nM1);
      float nM2 = fmaxf(M2, bM2);
      float e2a = __expf(M2 - nM2), e2b = __expf(bM2 - nM2);
      S1 = S1 * e1a + bS1 * e1b;
      S2 = S2 * e2a + bS2 * e2b;
      M1 = nM1; M2 = nM2;
      #pragma unroll
      for (int df = 0; df < 4; ++df)
        #pragma unroll
        for (int r = 0; r < 4; ++r) {
          O1[df][r] = O1[df][r] * e1a + o[df * 4 + r] * e1b;
          O2[df][r] = O2[df][r] * e2a + o[16 + df * 4 + r] * e2b;
        }
    }
    // ---- epilogue: gvm + combine halves ----
    float mv = mask[nrow];
    float mm = (mv < 0.5f) ? 1.0f : (mv > 0.5f ? -1.0f : -mv);
    float gvm = (mn - mx) * mm;
    float A1 = M1 + gvm, A2 = M2;
    float Mf = fmaxf(A1, A2);
    float w1 = __expf(A1 - Mf), w2 = __expf(A2 - Mf);
    float inv = 1.0f / (w1 * S1 + w2 * S2);
    #pragma unroll
    for (int df = 0; df < 4; ++df) {
      f16x4 ov;
      #pragma unroll
      for (int r = 0; r < 4; ++r)
        ov[r] = (f16)((w1 * O1[df][r] + w2 * O2[df][r]) * inv);
      *reinterpret_cast<f16x4*>(
          &mid[(size_t)nrow * INNER + h * DH + df * 16 + lk * 4]) = ov;
    }
  }
}

// ---------------------------------------------------------------------------
// out_mfma: out = mid(f16) @ Wo + bo.  grid (144, 5), 64 threads (1 wave).
// ---------------------------------------------------------------------------
__global__ __launch_bounds__(64) void out_mfma(
    const f16* __restrict__ mid, const f16* __restrict__ WoT,
    const float* __restrict__ bo, float* __restrict__ out)
{
  const int n0 = blockIdx.x * 16;
  const int o0 = blockIdx.y * 64;
  const int l = threadIdx.x, lq = l & 15, lk = l >> 4;
  f32x4 acc[4] = {};
  const f16* arow = mid + (size_t)(n0 + lq) * INNER;
  #pragma unroll
  for (int ks = 0; ks < 16; ++ks) {
    f16x8 a = *reinterpret_cast<const f16x8*>(&arow[ks * 32 + lk * 8]);
    #pragma unroll
    for (int df = 0; df < 4; ++df) {
      f16x8 b = *reinterpret_cast<const f16x8*>(
          &WoT[(size_t)(o0 + df * 16 + lq) * INNER + ks * 32 + lk * 8]);
      acc[df] = MFMA(a, b, acc[df]);
    }
  }
  #pragma unroll
  for (int df = 0; df < 4; ++df) {
    float bb = bo[o0 + df * 16 + lq];
    #pragma unroll
    for (int r = 0; r < 4; ++r) {
      int n = n0 + lk * 4 + r;
      out[(size_t)n * QD + o0 + df * 16 + lq] = acc[df][r] + bb;
    }
  }
}

// ---------------------------------------------------------------------------
extern "C" void kernel_launch(void* const* d_in, const int* in_sizes, int n_in,
                              void* d_out, int out_size, void* d_ws, size_t ws_size,
                              hipStream_t stream) {
  const float* x    = (const float*)d_in[0];
  const float* Wq   = (const float*)d_in[1];
  const float* Wo   = (const float*)d_in[2];
  const float* bo   = (const float*)d_in[3];
  const float* qinj = (const float*)d_in[4];
  const float* kinj = (const float*)d_in[5];
  const float* vinj = (const float*)d_in[6];
  const float* kcnt = (const float*)d_in[7];
  const float* vcnt = (const float*)d_in[8];
  const float* mask = (const float*)d_in[9];
  float* out = (float*)d_out;

  const size_t T = (size_t)HEADS * NTOK * DH;   // 1179648
  f16* qhat = (f16*)d_ws;
  f16* qc16 = qhat + T;
  f16* k16  = qc16 + T;
  f16* kc16 = k16  + T;
  f16* vt16 = kc16 + T;
  f16* vct16= vt16 + T;
  f16* mid  = vct16 + T;                 // [2304][512] f16 (written by attn2)
  // x16 + WqT live INSIDE the mid region (dead before attn2 writes mid):
  f16* x16  = mid;                       // 737280 f16
  f16* WqT  = mid + 737280;              // 163840 f16  (total 901120 <= T)
  f16* WoT  = mid + T;                   // persistent: after mid

  prep_cvt   <<<2088, 256, 0, stream>>>(qinj, kinj, kcnt, x, qc16, k16, kc16, x16);
  prep_tr    <<<dim3(36, 8, 2), 256, 0, stream>>>(vinj, vcnt, vt16, vct16);
  prep_trW   <<<dim3(40, 2), 256, 0, stream>>>(Wq, Wo, WqT, WoT);
  qblend_mfma<<<dim3(72, 8), 256, 0, stream>>>(x16, WqT, qinj, qhat);
  attn2      <<<1152, 256, 0, stream>>>(qhat, qc16, k16, kc16, vt16, vct16, mask, mid);
  out_mfma   <<<dim3(144, 5), 64, 0, stream>>>(mid, WoT, bo, out);
}

// Round 4
// 205.513 us; speedup vs baseline: 6.6207x; 1.2417x over previous
//
#include <hip/hip_runtime.h>
#include <math.h>

#define HEADS 8
#define NTOK  2304
#define DH    64
#define QD    320
#define INNER 512

typedef _Float16 f16;
typedef f16  f16x4 __attribute__((ext_vector_type(4)));
typedef f16  f16x8 __attribute__((ext_vector_type(8)));
typedef float f32x4 __attribute__((ext_vector_type(4)));

#define MFMA(a,b,c) __builtin_amdgcn_mfma_f32_16x16x32_f16((a),(b),(c),0,0,0)

// ---------------------------------------------------------------------------
// prep_cvt: fp32->f16 flat converts: qinj->qc16(x1), kinj->k16(x1),
// kcnt->kc16(x0.125), x->x16(x1). 534528 x8-chunks = 2088 blocks.
// ---------------------------------------------------------------------------
__global__ __launch_bounds__(256) void prep_cvt(
    const float* __restrict__ qi, const float* __restrict__ ki,
    const float* __restrict__ kc, const float* __restrict__ x,
    f16* __restrict__ oq, f16* __restrict__ ok, f16* __restrict__ okc,
    f16* __restrict__ ox)
{
  int i = blockIdx.x * 256 + threadIdx.x;
  const float* src; f16* dst; float s = 1.0f; int off;
  if (i < 147456)      { src = qi; dst = oq;  off = i; }
  else if (i < 294912) { src = ki; dst = ok;  off = i - 147456; }
  else if (i < 442368) { src = kc; dst = okc; off = i - 294912; s = 0.125f; }
  else                 { src = x;  dst = ox;  off = i - 442368; }
  float4 a = reinterpret_cast<const float4*>(src)[off * 2];
  float4 b = reinterpret_cast<const float4*>(src)[off * 2 + 1];
  f16x8 o;
  o[0] = (f16)(a.x * s); o[1] = (f16)(a.y * s);
  o[2] = (f16)(a.z * s); o[3] = (f16)(a.w * s);
  o[4] = (f16)(b.x * s); o[5] = (f16)(b.y * s);
  o[6] = (f16)(b.z * s); o[7] = (f16)(b.w * s);
  *reinterpret_cast<f16x8*>(&dst[(size_t)off * 8]) = o;
}

// ---------------------------------------------------------------------------
// prep_tr: v / v_cnt fp32 [h][n][d] -> fp16 transposed [h][d][n]
// ---------------------------------------------------------------------------
__global__ __launch_bounds__(256) void prep_tr(
    const float* __restrict__ v, const float* __restrict__ vc,
    f16* __restrict__ vt, f16* __restrict__ vct)
{
  __shared__ float T[64][65];
  const float* src = blockIdx.z ? vc : v;
  f16* dst = blockIdx.z ? vct : vt;
  const int h = blockIdx.y, n0 = blockIdx.x * 64;
  const int tid = threadIdx.x;
  const size_t base = ((size_t)h * NTOK + n0) * DH;
  for (int it = 0; it < 4; ++it) {
    int idx = tid + it * 256;
    int n = idx >> 4, d0 = (idx & 15) * 4;
    float4 a = *reinterpret_cast<const float4*>(&src[base + (size_t)n * DH + d0]);
    T[n][d0] = a.x; T[n][d0 + 1] = a.y; T[n][d0 + 2] = a.z; T[n][d0 + 3] = a.w;
  }
  __syncthreads();
  for (int it = 0; it < 2; ++it) {
    int idx = tid + it * 256;
    int d = idx >> 3, c0 = (idx & 7) * 8;
    f16x8 o;
    #pragma unroll
    for (int i = 0; i < 8; ++i) o[i] = (f16)T[c0 + i][d];
    *reinterpret_cast<f16x8*>(&dst[(size_t)(h * 64 + d) * NTOK + n0 + c0]) = o;
  }
}

// ---------------------------------------------------------------------------
// prep_trW: Wq [320][512] -> WqT f16 [512][320]; Wo [512][320] -> WoT [320][512]
// ---------------------------------------------------------------------------
__global__ __launch_bounds__(256) void prep_trW(
    const float* __restrict__ Wq, const float* __restrict__ Wo,
    f16* __restrict__ WqT, f16* __restrict__ WoT)
{
  __shared__ float T[64][65];
  const int z = blockIdx.y;
  const float* src = z ? Wo : Wq;
  f16* dst = z ? WoT : WqT;
  const int R = z ? INNER : QD;
  const int C = z ? QD : INNER;
  const int ctiles = C >> 6;
  const int rt = blockIdx.x / ctiles, ct = blockIdx.x % ctiles;
  const int tid = threadIdx.x;
  for (int it = 0; it < 4; ++it) {
    int idx = tid + it * 256;
    int r = idx >> 4, c4 = (idx & 15) * 4;
    float4 a = *reinterpret_cast<const float4*>(&src[(size_t)(rt * 64 + r) * C + ct * 64 + c4]);
    T[r][c4] = a.x; T[r][c4 + 1] = a.y; T[r][c4 + 2] = a.z; T[r][c4 + 3] = a.w;
  }
  __syncthreads();
  for (int it = 0; it < 4; ++it) {
    int idx = tid + it * 256;
    int c = idx >> 4, r4 = (idx & 15) * 4;
    f16x4 o;
    #pragma unroll
    for (int i = 0; i < 4; ++i) o[i] = (f16)T[r4 + i][c];
    *reinterpret_cast<f16x4*>(&dst[(size_t)(ct * 64 + c) * R + rt * 64 + r4]) = o;
  }
}

// ---------------------------------------------------------------------------
// qblend_mfma: qhat[h][n][d] = 0.09375*(qinj + x@Wq), f16 out, MFMA.
// ---------------------------------------------------------------------------
__global__ __launch_bounds__(256) void qblend_mfma(
    const f16* __restrict__ x16, const f16* __restrict__ WqT,
    const float* __restrict__ qinj, f16* __restrict__ qhat)
{
  const int qt = blockIdx.x, h = blockIdx.y;
  const int n0 = qt * 32;
  const int tid = threadIdx.x;
  const int w = tid >> 6, l = tid & 63, lq = l & 15, lk = l >> 4;
  const int qsub = w & 1, ch = w >> 1;
  f32x4 acc[2] = {};
  const f16* arow = x16 + (size_t)(n0 + qsub * 16 + lq) * QD;
  #pragma unroll
  for (int ks = 0; ks < 10; ++ks) {
    f16x8 a = *reinterpret_cast<const f16x8*>(&arow[ks * 32 + lk * 8]);
    #pragma unroll
    for (int df = 0; df < 2; ++df) {
      const f16* brow = WqT + (size_t)(h * 64 + ch * 32 + df * 16 + lq) * QD;
      f16x8 b = *reinterpret_cast<const f16x8*>(&brow[ks * 32 + lk * 8]);
      acc[df] = MFMA(a, b, acc[df]);
    }
  }
  #pragma unroll
  for (int df = 0; df < 2; ++df)
    #pragma unroll
    for (int r = 0; r < 4; ++r) {
      int n = n0 + qsub * 16 + lk * 4 + r;
      int d = ch * 32 + df * 16 + lq;
      size_t idx = ((size_t)h * NTOK + n) * DH + d;
      qhat[idx] = (f16)(0.09375f * (qinj[idx] + acc[df][r]));
    }
}

// ---------------------------------------------------------------------------
// attn3: swapped-MFMA fused attention, KV-split x3, 3-wave blocks (192 thr).
// grid 1152 = 144 qtiles x 8 heads; h = bid&7 (XCD pin), qt = bid>>3
// (16 q-rows). Wave w in {0,1,2} does key tiles [12w, 12w+12).
// No barriers in the main loop (waves independent); 2 barriers at merge.
// ---------------------------------------------------------------------------
__global__ __launch_bounds__(192, 4) void attn3(
    const f16* __restrict__ qhat, const f16* __restrict__ qc16,
    const f16* __restrict__ k16,  const f16* __restrict__ kc16,
    const f16* __restrict__ vt16, const f16* __restrict__ vct16,
    const float* __restrict__ mask, f16* __restrict__ mid)
{
  __shared__ __align__(16) unsigned char smem[19456];

  const int bid = blockIdx.x;
  const int h = bid & 7, qt = bid >> 3;
  const int n0 = qt * 16;
  const int tid = threadIdx.x;
  const int w = tid >> 6, l = tid & 63;
  const int lq = l & 15, lk = l >> 4;
  const size_t hb = (size_t)h * NTOK * DH;
  f16* P1 = reinterpret_cast<f16*>(smem) + w * 2304;   // [16][72] f16
  f16* P2 = P1 + 16 * 72;                               // wave-private

  const int nrow = n0 + lq;
  f16x8 qB[2], qcB[2];
  {
    const size_t qr = hb + (size_t)nrow * DH;
    #pragma unroll
    for (int ks = 0; ks < 2; ++ks) {
      qB [ks] = *reinterpret_cast<const f16x8*>(&qhat[qr + ks * 32 + lk * 8]);
      qcB[ks] = *reinterpret_cast<const f16x8*>(&qc16[qr + ks * 32 + lk * 8]);
    }
  }
  // lane base pointers for K/V fragment rows
  const f16* kL  = k16  + hb + (size_t)lq * DH + lk * 8;   // + (j0+jf*16)*DH + ks*32
  const f16* kcL = kc16 + hb + (size_t)lq * DH + lk * 8;
  const f16* vL  = vt16  + (size_t)(h * DH + lq) * NTOK + lk * 8;  // + df*16*NTOK + j0 + ks*32
  const f16* vcL = vct16 + (size_t)(h * DH + lq) * NTOK + lk * 8;

  float M1 = -INFINITY, S1 = 0.f, M2 = -INFINITY, S2 = 0.f;
  float mn = INFINITY, mx = -INFINITY;
  f32x4 O1[4] = {}, O2[4] = {};

  for (int t = 0; t < 12; ++t) {
    const int j0 = (w * 12 + t) * 64;
    // ---- QK^T (swapped): s[key][q]; s3 reduced on the fly ----
    f32x4 s1[4] = {}, s2[4] = {};
    float mM = -INFINITY;
    __builtin_amdgcn_s_setprio(1);
    #pragma unroll
    for (int jf = 0; jf < 4; ++jf) {
      f32x4 t3 = {};
      #pragma unroll
      for (int ks = 0; ks < 2; ++ks) {
        const size_t ko = (size_t)(j0 + jf * 16) * DH + ks * 32;
        f16x8 aK  = *reinterpret_cast<const f16x8*>(kL  + ko);
        f16x8 aKC = *reinterpret_cast<const f16x8*>(kcL + ko);
        s1[jf] = MFMA(aK,  qB [ks], s1[jf]);
        t3     = MFMA(aK,  qcB[ks], t3);
        s2[jf] = MFMA(aKC, qcB[ks], s2[jf]);
      }
      mM = fmaxf(mM, fmaxf(fmaxf(t3[0], t3[1]), fmaxf(t3[2], t3[3])));
    }
    __builtin_amdgcn_s_setprio(0);
    // ---- in-lane reductions (16 keys) + 2 shfls across lk-groups ----
    float mS, mC, nC;
    {
      float a0 = fmaxf(fmaxf(s1[0][0], s1[0][1]), fmaxf(s1[0][2], s1[0][3]));
      float a1 = fmaxf(fmaxf(s1[1][0], s1[1][1]), fmaxf(s1[1][2], s1[1][3]));
      float a2 = fmaxf(fmaxf(s1[2][0], s1[2][1]), fmaxf(s1[2][2], s1[2][3]));
      float a3 = fmaxf(fmaxf(s1[3][0], s1[3][1]), fmaxf(s1[3][2], s1[3][3]));
      mS = fmaxf(fmaxf(a0, a1), fmaxf(a2, a3));
      a0 = fmaxf(fmaxf(s2[0][0], s2[0][1]), fmaxf(s2[0][2], s2[0][3]));
      a1 = fmaxf(fmaxf(s2[1][0], s2[1][1]), fmaxf(s2[1][2], s2[1][3]));
      a2 = fmaxf(fmaxf(s2[2][0], s2[2][1]), fmaxf(s2[2][2], s2[2][3]));
      a3 = fmaxf(fmaxf(s2[3][0], s2[3][1]), fmaxf(s2[3][2], s2[3][3]));
      mC = fmaxf(fmaxf(a0, a1), fmaxf(a2, a3));
      a0 = fminf(fminf(s2[0][0], s2[0][1]), fminf(s2[0][2], s2[0][3]));
      a1 = fminf(fminf(s2[1][0], s2[1][1]), fminf(s2[1][2], s2[1][3]));
      a2 = fminf(fminf(s2[2][0], s2[2][1]), fminf(s2[2][2], s2[2][3]));
      a3 = fminf(fminf(s2[3][0], s2[3][1]), fminf(s2[3][2], s2[3][3]));
      nC = fminf(fminf(a0, a1), fminf(a2, a3));
    }
    mS = fmaxf(mS, __shfl_xor(mS, 16)); mS = fmaxf(mS, __shfl_xor(mS, 32));
    mC = fmaxf(mC, __shfl_xor(mC, 16)); mC = fmaxf(mC, __shfl_xor(mC, 32));
    nC = fminf(nC, __shfl_xor(nC, 16)); nC = fminf(nC, __shfl_xor(nC, 32));
    mM = fmaxf(mM, __shfl_xor(mM, 16)); mM = fmaxf(mM, __shfl_xor(mM, 32));
    mn = fminf(mn, nC);
    mx = fmaxf(mx, mM);
    float nM1 = fmaxf(M1, mS), nM2 = fmaxf(M2, mC);
    float sc1 = __expf(M1 - nM1), sc2 = __expf(M2 - nM2);
    M1 = nM1; M2 = nM2;
    float ps1 = 0.f, ps2 = 0.f;
    #pragma unroll
    for (int jf = 0; jf < 4; ++jf) {
      #pragma unroll
      for (int r = 0; r < 4; ++r) {
        float p1 = __expf(s1[jf][r] - nM1); s1[jf][r] = p1;
        float p2 = __expf(s2[jf][r] - nM2); s2[jf][r] = p2;
      }
      ps1 += (s1[jf][0] + s1[jf][1]) + (s1[jf][2] + s1[jf][3]);
      ps2 += (s2[jf][0] + s2[jf][1]) + (s2[jf][2] + s2[jf][3]);
      // packed P write (wave-private LDS, no barrier)
      f16x4 w1, w2;
      #pragma unroll
      for (int r = 0; r < 4; ++r) { w1[r] = (f16)s1[jf][r]; w2[r] = (f16)s2[jf][r]; }
      *reinterpret_cast<f16x4*>(&P1[lq * 72 + jf * 16 + lk * 4]) = w1;
      *reinterpret_cast<f16x4*>(&P2[lq * 72 + jf * 16 + lk * 4]) = w2;
    }
    ps1 += __shfl_xor(ps1, 16); ps1 += __shfl_xor(ps1, 32);
    ps2 += __shfl_xor(ps2, 16); ps2 += __shfl_xor(ps2, 32);
    S1 = S1 * sc1 + ps1;
    S2 = S2 * sc2 + ps2;
    // ---- rescale O ----
    #pragma unroll
    for (int df = 0; df < 4; ++df) { O1[df] *= sc1; O2[df] *= sc2; }
    // ---- PV (swapped): O[d][q] ----
    __builtin_amdgcn_s_setprio(1);
    #pragma unroll
    for (int ks = 0; ks < 2; ++ks) {
      f16x8 pB1 = *reinterpret_cast<const f16x8*>(&P1[lq * 72 + ks * 32 + lk * 8]);
      f16x8 pB2 = *reinterpret_cast<const f16x8*>(&P2[lq * 72 + ks * 32 + lk * 8]);
      #pragma unroll
      for (int df = 0; df < 4; ++df) {
        const size_t vo = (size_t)df * 16 * NTOK + j0 + ks * 32;
        f16x8 aV  = *reinterpret_cast<const f16x8*>(vL  + vo);
        f16x8 aVC = *reinterpret_cast<const f16x8*>(vcL + vo);
        O1[df] = MFMA(aV,  pB1, O1[df]);
        O2[df] = MFMA(aVC, pB2, O2[df]);
      }
    }
    __builtin_amdgcn_s_setprio(0);
  }

  // ---- merge 3 KV-thirds (LDS reused; P regions dead) ----
  float* mF = reinterpret_cast<float*>(smem);           // [2][64][6]
  float* mO = reinterpret_cast<float*>(smem + 3072);    // [2][64][32]
  __syncthreads();
  if (w > 0) {
    float* f = mF + ((w - 1) * 64 + l) * 6;
    f[0] = M1; f[1] = S1; f[2] = M2; f[3] = S2; f[4] = mn; f[5] = mx;
    float* o = mO + ((w - 1) * 64 + l) * 32;
    #pragma unroll
    for (int df = 0; df < 4; ++df)
      #pragma unroll
      for (int r = 0; r < 4; ++r) {
        o[df * 4 + r]      = O1[df][r];
        o[16 + df * 4 + r] = O2[df][r];
      }
  }
  __syncthreads();
  if (w == 0) {
    #pragma unroll
    for (int p = 0; p < 2; ++p) {
      const float* f = mF + (p * 64 + l) * 6;
      const float* o = mO + (p * 64 + l) * 32;
      float bM1 = f[0], bS1 = f[1], bM2 = f[2], bS2 = f[3];
      mn = fminf(mn, f[4]); mx = fmaxf(mx, f[5]);
      float nM1 = fmaxf(M1, bM1);
      float e1a = __expf(M1 - nM1), e1b = __expf(bM1 - nM1);
      float nM2 = fmaxf(M2, bM2);
      float e2a = __expf(M2 - nM2), e2b = __expf(bM2 - nM2);
      S1 = S1 * e1a + bS1 * e1b;
      S2 = S2 * e2a + bS2 * e2b;
      M1 = nM1; M2 = nM2;
      #pragma unroll
      for (int df = 0; df < 4; ++df)
        #pragma unroll
        for (int r = 0; r < 4; ++r) {
          O1[df][r] = O1[df][r] * e1a + o[df * 4 + r] * e1b;
          O2[df][r] = O2[df][r] * e2a + o[16 + df * 4 + r] * e2b;
        }
    }
    float mv = mask[nrow];
    float mm = (mv < 0.5f) ? 1.0f : (mv > 0.5f ? -1.0f : -mv);
    float gvm = (mn - mx) * mm;
    float A1 = M1 + gvm, A2 = M2;
    float Mf = fmaxf(A1, A2);
    float w1 = __expf(A1 - Mf), w2 = __expf(A2 - Mf);
    float inv = 1.0f / (w1 * S1 + w2 * S2);
    #pragma unroll
    for (int df = 0; df < 4; ++df) {
      f16x4 ov;
      #pragma unroll
      for (int r = 0; r < 4; ++r)
        ov[r] = (f16)((w1 * O1[df][r] + w2 * O2[df][r]) * inv);
      *reinterpret_cast<f16x4*>(
          &mid[(size_t)nrow * INNER + h * DH + df * 16 + lk * 4]) = ov;
    }
  }
}

// ---------------------------------------------------------------------------
// out_mfma: out = mid(f16) @ Wo + bo.  grid (144, 5), 64 threads (1 wave).
// ---------------------------------------------------------------------------
__global__ __launch_bounds__(64) void out_mfma(
    const f16* __restrict__ mid, const f16* __restrict__ WoT,
    const float* __restrict__ bo, float* __restrict__ out)
{
  const int n0 = blockIdx.x * 16;
  const int o0 = blockIdx.y * 64;
  const int l = threadIdx.x, lq = l & 15, lk = l >> 4;
  f32x4 acc[4] = {};
  const f16* arow = mid + (size_t)(n0 + lq) * INNER;
  #pragma unroll
  for (int ks = 0; ks < 16; ++ks) {
    f16x8 a = *reinterpret_cast<const f16x8*>(&arow[ks * 32 + lk * 8]);
    #pragma unroll
    for (int df = 0; df < 4; ++df) {
      f16x8 b = *reinterpret_cast<const f16x8*>(
          &WoT[(size_t)(o0 + df * 16 + lq) * INNER + ks * 32 + lk * 8]);
      acc[df] = MFMA(a, b, acc[df]);
    }
  }
  #pragma unroll
  for (int df = 0; df < 4; ++df) {
    float bb = bo[o0 + df * 16 + lq];
    #pragma unroll
    for (int r = 0; r < 4; ++r) {
      int n = n0 + lk * 4 + r;
      out[(size_t)n * QD + o0 + df * 16 + lq] = acc[df][r] + bb;
    }
  }
}

// ---------------------------------------------------------------------------
extern "C" void kernel_launch(void* const* d_in, const int* in_sizes, int n_in,
                              void* d_out, int out_size, void* d_ws, size_t ws_size,
                              hipStream_t stream) {
  const float* x    = (const float*)d_in[0];
  const float* Wq   = (const float*)d_in[1];
  const float* Wo   = (const float*)d_in[2];
  const float* bo   = (const float*)d_in[3];
  const float* qinj = (const float*)d_in[4];
  const float* kinj = (const float*)d_in[5];
  const float* vinj = (const float*)d_in[6];
  const float* kcnt = (const float*)d_in[7];
  const float* vcnt = (const float*)d_in[8];
  const float* mask = (const float*)d_in[9];
  float* out = (float*)d_out;

  const size_t T = (size_t)HEADS * NTOK * DH;   // 1179648
  f16* qhat = (f16*)d_ws;
  f16* qc16 = qhat + T;
  f16* k16  = qc16 + T;
  f16* kc16 = k16  + T;
  f16* vt16 = kc16 + T;
  f16* vct16= vt16 + T;
  f16* mid  = vct16 + T;                 // [2304][512] f16 (written by attn3)
  // x16 + WqT live INSIDE the mid region (dead before attn3 writes mid):
  f16* x16  = mid;                       // 737280 f16
  f16* WqT  = mid + 737280;              // 163840 f16  (total 901120 <= T)
  f16* WoT  = mid + T;                   // persistent: after mid

  prep_cvt   <<<2088, 256, 0, stream>>>(qinj, kinj, kcnt, x, qc16, k16, kc16, x16);
  prep_tr    <<<dim3(36, 8, 2), 256, 0, stream>>>(vinj, vcnt, vt16, vct16);
  prep_trW   <<<dim3(40, 2), 256, 0, stream>>>(Wq, Wo, WqT, WoT);
  qblend_mfma<<<dim3(72, 8), 256, 0, stream>>>(x16, WqT, qinj, qhat);
  attn3      <<<1152, 192, 0, stream>>>(qhat, qc16, k16, kc16, vt16, vct16, mask, mid);
  out_mfma   <<<dim3(144, 5), 64, 0, stream>>>(mid, WoT, bo, out);
}

// Round 5
// 121.008 us; speedup vs baseline: 11.2442x; 1.6983x over previous
//
#include <hip/hip_runtime.h>
#include <math.h>

#define HEADS 8
#define NTOK  2304
#define DH    64
#define QD    320
#define INNER 512
#define NSPLIT 2
#define TPS    18   // key tiles per split (36 total)

typedef _Float16 f16;
typedef f16  f16x4 __attribute__((ext_vector_type(4)));
typedef f16  f16x8 __attribute__((ext_vector_type(8)));
typedef float f32x4 __attribute__((ext_vector_type(4)));

#define MFMA(a,b,c) __builtin_amdgcn_mfma_f32_16x16x32_f16((a),(b),(c),0,0,0)

#define GLDS(gp, lp) __builtin_amdgcn_global_load_lds(                      \
    (const __attribute__((address_space(1))) void*)(gp),                    \
    (__attribute__((address_space(3))) void*)(lp), 16, 0, 0)

static __device__ __forceinline__ unsigned packf16(float a, float b) {
  union { f16 h; unsigned short u; } ca, cb;
  ca.h = (f16)a; cb.h = (f16)b;
  return (unsigned)ca.u | ((unsigned)cb.u << 16);
}

// ---------------------------------------------------------------------------
// prep_cvt: fp32->f16 flat converts: qinj->qc16(x1), kinj->k16(x1),
// kcnt->kc16(x0.125), x->x16(x1).
// ---------------------------------------------------------------------------
__global__ __launch_bounds__(256) void prep_cvt(
    const float* __restrict__ qi, const float* __restrict__ ki,
    const float* __restrict__ kc, const float* __restrict__ x,
    f16* __restrict__ oq, f16* __restrict__ ok, f16* __restrict__ okc,
    f16* __restrict__ ox)
{
  int i = blockIdx.x * 256 + threadIdx.x;
  const float* src; f16* dst; float s = 1.0f; int off;
  if (i < 147456)      { src = qi; dst = oq;  off = i; }
  else if (i < 294912) { src = ki; dst = ok;  off = i - 147456; }
  else if (i < 442368) { src = kc; dst = okc; off = i - 294912; s = 0.125f; }
  else                 { src = x;  dst = ox;  off = i - 442368; }
  float4 a = reinterpret_cast<const float4*>(src)[off * 2];
  float4 b = reinterpret_cast<const float4*>(src)[off * 2 + 1];
  f16x8 o;
  o[0] = (f16)(a.x * s); o[1] = (f16)(a.y * s);
  o[2] = (f16)(a.z * s); o[3] = (f16)(a.w * s);
  o[4] = (f16)(b.x * s); o[5] = (f16)(b.y * s);
  o[6] = (f16)(b.z * s); o[7] = (f16)(b.w * s);
  *reinterpret_cast<f16x8*>(&dst[(size_t)off * 8]) = o;
}

// ---------------------------------------------------------------------------
// prep_tr: v / v_cnt fp32 [h][n][d] -> fp16 transposed [h][d][n]
// ---------------------------------------------------------------------------
__global__ __launch_bounds__(256) void prep_tr(
    const float* __restrict__ v, const float* __restrict__ vc,
    f16* __restrict__ vt, f16* __restrict__ vct)
{
  __shared__ float T[64][65];
  const float* src = blockIdx.z ? vc : v;
  f16* dst = blockIdx.z ? vct : vt;
  const int h = blockIdx.y, n0 = blockIdx.x * 64;
  const int tid = threadIdx.x;
  const size_t base = ((size_t)h * NTOK + n0) * DH;
  for (int it = 0; it < 4; ++it) {
    int idx = tid + it * 256;
    int n = idx >> 4, d0 = (idx & 15) * 4;
    float4 a = *reinterpret_cast<const float4*>(&src[base + (size_t)n * DH + d0]);
    T[n][d0] = a.x; T[n][d0 + 1] = a.y; T[n][d0 + 2] = a.z; T[n][d0 + 3] = a.w;
  }
  __syncthreads();
  for (int it = 0; it < 2; ++it) {
    int idx = tid + it * 256;
    int d = idx >> 3, c0 = (idx & 7) * 8;
    f16x8 o;
    #pragma unroll
    for (int i = 0; i < 8; ++i) o[i] = (f16)T[c0 + i][d];
    *reinterpret_cast<f16x8*>(&dst[(size_t)(h * 64 + d) * NTOK + n0 + c0]) = o;
  }
}

// ---------------------------------------------------------------------------
// prep_trW: Wq -> WqT f16; Wo -> WoT f16 (transposed)
// ---------------------------------------------------------------------------
__global__ __launch_bounds__(256) void prep_trW(
    const float* __restrict__ Wq, const float* __restrict__ Wo,
    f16* __restrict__ WqT, f16* __restrict__ WoT)
{
  __shared__ float T[64][65];
  const int z = blockIdx.y;
  const float* src = z ? Wo : Wq;
  f16* dst = z ? WoT : WqT;
  const int R = z ? INNER : QD;
  const int C = z ? QD : INNER;
  const int ctiles = C >> 6;
  const int rt = blockIdx.x / ctiles, ct = blockIdx.x % ctiles;
  const int tid = threadIdx.x;
  for (int it = 0; it < 4; ++it) {
    int idx = tid + it * 256;
    int r = idx >> 4, c4 = (idx & 15) * 4;
    float4 a = *reinterpret_cast<const float4*>(&src[(size_t)(rt * 64 + r) * C + ct * 64 + c4]);
    T[r][c4] = a.x; T[r][c4 + 1] = a.y; T[r][c4 + 2] = a.z; T[r][c4 + 3] = a.w;
  }
  __syncthreads();
  for (int it = 0; it < 4; ++it) {
    int idx = tid + it * 256;
    int c = idx >> 4, r4 = (idx & 15) * 4;
    f16x4 o;
    #pragma unroll
    for (int i = 0; i < 4; ++i) o[i] = (f16)T[r4 + i][c];
    *reinterpret_cast<f16x4*>(&dst[(size_t)(ct * 64 + c) * R + rt * 64 + r4]) = o;
  }
}

// ---------------------------------------------------------------------------
// qblend_mfma: qhat[h][n][d] = 0.09375*(qinj + x@Wq), f16 out, MFMA.
// ---------------------------------------------------------------------------
__global__ __launch_bounds__(256) void qblend_mfma(
    const f16* __restrict__ x16, const f16* __restrict__ WqT,
    const float* __restrict__ qinj, f16* __restrict__ qhat)
{
  const int qt = blockIdx.x, h = blockIdx.y;
  const int n0 = qt * 32;
  const int tid = threadIdx.x;
  const int w = tid >> 6, l = tid & 63, lq = l & 15, lk = l >> 4;
  const int qsub = w & 1, ch = w >> 1;
  f32x4 acc[2] = {};
  const f16* arow = x16 + (size_t)(n0 + qsub * 16 + lq) * QD;
  #pragma unroll
  for (int ks = 0; ks < 10; ++ks) {
    f16x8 a = *reinterpret_cast<const f16x8*>(&arow[ks * 32 + lk * 8]);
    #pragma unroll
    for (int df = 0; df < 2; ++df) {
      const f16* brow = WqT + (size_t)(h * 64 + ch * 32 + df * 16 + lq) * QD;
      f16x8 b = *reinterpret_cast<const f16x8*>(&brow[ks * 32 + lk * 8]);
      acc[df] = MFMA(a, b, acc[df]);
    }
  }
  #pragma unroll
  for (int df = 0; df < 2; ++df)
    #pragma unroll
    for (int r = 0; r < 4; ++r) {
      int n = n0 + qsub * 16 + lk * 4 + r;
      int d = ch * 32 + df * 16 + lq;
      size_t idx = ((size_t)h * NTOK + n) * DH + d;
      qhat[idx] = (f16)(0.09375f * (qinj[idx] + acc[df][r]));
    }
}

// ---------------------------------------------------------------------------
// attn_part: stage 1 of split-K fused attention. 2-phase LDS pipeline:
// K/KC/VT/VCT double-buffered (64 KB), staged via global_load_lds with
// XOR-swizzled SOURCE addresses (linear dest; read applies the same swizzle).
// grid 576 = h(8) x qt(36, 64 q-rows) x split(2, 18 key-tiles each).
// 4 waves, wave w owns q-rows qt*64 + 16w..+16. Swapped MFMA; P in-register
// via pack + ds_bpermute. Partials (M,S,mn,mx,O1,O2) -> part[].
// ---------------------------------------------------------------------------
__global__ __launch_bounds__(256, 2) void attn_part(
    const f16* __restrict__ qhat, const f16* __restrict__ qc16,
    const f16* __restrict__ k16,  const f16* __restrict__ kc16,
    const f16* __restrict__ vt16, const f16* __restrict__ vct16,
    float* __restrict__ part)
{
  __shared__ f16 smem[2][4][4096];   // [buf][K,KC,VT,VCT][64 rows x 64]

  const int bid = blockIdx.x;
  const int h  = bid & 7;            // head == XCD (round-robin dispatch)
  const int r6 = bid >> 3;           // 0..71
  const int qt = r6 >> 1;
  const int sp = r6 & 1;
  const int tid = threadIdx.x;
  const int w = tid >> 6, l = tid & 63;
  const int lq = l & 15, lk = l >> 4;
  const size_t hb = (size_t)h * NTOK * DH;
  const int nrow = qt * 64 + w * 16 + lq;

  // Q fragments (B-operand, 16B contiguous per lane)
  f16x8 qB[2], qcB[2];
  {
    const size_t qr = hb + (size_t)nrow * DH;
    #pragma unroll
    for (int ks = 0; ks < 2; ++ks) {
      qB [ks] = *reinterpret_cast<const f16x8*>(&qhat[qr + ks * 32 + lk * 8]);
      qcB[ks] = *reinterpret_cast<const f16x8*>(&qc16[qr + ks * 32 + lk * 8]);
    }
  }

  // --- staging geometry: chunk i = c*256 + tid; LDS byte 16*i (linear).
  // desired LDS image: LDS[row][slot] = G[row][slot ^ (row&7)]  (16B slots)
  const int i0 = tid,        row0 = i0 >> 3, sl0 = i0 & 7;
  const int i1 = 256 + tid,  row1 = i1 >> 3, sl1 = i1 & 7;
  const int sw0 = (sl0 ^ (row0 & 7)) * 8;   // f16 offset within 64-elem row
  const int sw1 = (sl1 ^ (row1 & 7)) * 8;
  const f16* gK  = k16  + hb;
  const f16* gKC = kc16 + hb;
  const f16* gVT = vt16  + (size_t)h * DH * NTOK;
  const f16* gVCT= vct16 + (size_t)h * DH * NTOK;
  const int lb = __builtin_amdgcn_readfirstlane((tid & 192) * 8); // w*512 f16

  #define STAGE(nb, j0)                                                      \
    do {                                                                     \
      GLDS(gK  + (size_t)((j0) + row0) * 64 + sw0, &smem[nb][0][lb]);        \
      GLDS(gK  + (size_t)((j0) + row1) * 64 + sw1, &smem[nb][0][2048 + lb]); \
      GLDS(gKC + (size_t)((j0) + row0) * 64 + sw0, &smem[nb][1][lb]);        \
      GLDS(gKC + (size_t)((j0) + row1) * 64 + sw1, &smem[nb][1][2048 + lb]); \
      GLDS(gVT + (size_t)row0 * NTOK + (j0) + sw0, &smem[nb][2][lb]);        \
      GLDS(gVT + (size_t)row1 * NTOK + (j0) + sw1, &smem[nb][2][2048 + lb]); \
      GLDS(gVCT+ (size_t)row0 * NTOK + (j0) + sw0, &smem[nb][3][lb]);        \
      GLDS(gVCT+ (size_t)row1 * NTOK + (j0) + sw1, &smem[nb][3][2048 + lb]); \
    } while (0)

  // read-side swizzled offsets (f16 units): row r, want col m*8:
  //   idx = r*64 + ((m*8) ^ ((r&7)*8));  here r&7 == lq&7 for all frags
  const int swz = (lq & 7) * 8;
  int xo[2];
  #pragma unroll
  for (int ks = 0; ks < 2; ++ks) xo[ks] = ((ks * 32 + lk * 8) ^ swz);

  // bpermute source lanes for P redistribution (byte addresses)
  int srcl[4];
  #pragma unroll
  for (int t = 0; t < 4; ++t)
    srcl[t] = (lq + 16 * (2 * (lk & 1) + (t >> 1))) * 4;
  const int hi2 = lk >> 1;   // selects jf = 2ks+1 half

  float M1 = -INFINITY, S1 = 0.f, M2 = -INFINITY, S2 = 0.f;
  float mn = INFINITY, mx = -INFINITY;
  f32x4 O1[4] = {}, O2[4] = {};

  STAGE(0, sp * (TPS * 64));
  __syncthreads();

  int cur = 0;
  for (int t = 0; t < TPS; ++t) {
    const int j0 = (sp * TPS + t) * 64;
    if (t < TPS - 1) STAGE(cur ^ 1, j0 + 64);

    const f16* Kb  = &smem[cur][0][0];
    const f16* KCb = &smem[cur][1][0];
    const f16* VTb = &smem[cur][2][0];
    const f16* VCb = &smem[cur][3][0];

    // ---- QK^T (swapped): s[key][q] ----
    f32x4 s1[4] = {}, s2[4] = {};
    float mM = -INFINITY;
    #pragma unroll
    for (int jf = 0; jf < 4; ++jf) {
      f32x4 t3 = {};
      const int rb = (jf * 16 + lq) * 64;
      #pragma unroll
      for (int ks = 0; ks < 2; ++ks) {
        f16x8 aK  = *reinterpret_cast<const f16x8*>(&Kb [rb + xo[ks]]);
        f16x8 aKC = *reinterpret_cast<const f16x8*>(&KCb[rb + xo[ks]]);
        s1[jf] = MFMA(aK,  qB [ks], s1[jf]);
        t3     = MFMA(aK,  qcB[ks], t3);
        s2[jf] = MFMA(aKC, qcB[ks], s2[jf]);
      }
      mM = fmaxf(mM, fmaxf(fmaxf(t3[0], t3[1]), fmaxf(t3[2], t3[3])));
    }

    // ---- reductions: in-lane over 16 keys + 2 shfls across lk groups ----
    float mS, mC, nC;
    {
      float a0 = fmaxf(fmaxf(s1[0][0], s1[0][1]), fmaxf(s1[0][2], s1[0][3]));
      float a1 = fmaxf(fmaxf(s1[1][0], s1[1][1]), fmaxf(s1[1][2], s1[1][3]));
      float a2 = fmaxf(fmaxf(s1[2][0], s1[2][1]), fmaxf(s1[2][2], s1[2][3]));
      float a3 = fmaxf(fmaxf(s1[3][0], s1[3][1]), fmaxf(s1[3][2], s1[3][3]));
      mS = fmaxf(fmaxf(a0, a1), fmaxf(a2, a3));
      a0 = fmaxf(fmaxf(s2[0][0], s2[0][1]), fmaxf(s2[0][2], s2[0][3]));
      a1 = fmaxf(fmaxf(s2[1][0], s2[1][1]), fmaxf(s2[1][2], s2[1][3]));
      a2 = fmaxf(fmaxf(s2[2][0], s2[2][1]), fmaxf(s2[2][2], s2[2][3]));
      a3 = fmaxf(fmaxf(s2[3][0], s2[3][1]), fmaxf(s2[3][2], s2[3][3]));
      mC = fmaxf(fmaxf(a0, a1), fmaxf(a2, a3));
      a0 = fminf(fminf(s2[0][0], s2[0][1]), fminf(s2[0][2], s2[0][3]));
      a1 = fminf(fminf(s2[1][0], s2[1][1]), fminf(s2[1][2], s2[1][3]));
      a2 = fminf(fminf(s2[2][0], s2[2][1]), fminf(s2[2][2], s2[2][3]));
      a3 = fminf(fminf(s2[3][0], s2[3][1]), fminf(s2[3][2], s2[3][3]));
      nC = fminf(fminf(a0, a1), fminf(a2, a3));
    }
    mS = fmaxf(mS, __shfl_xor(mS, 16)); mS = fmaxf(mS, __shfl_xor(mS, 32));
    mC = fmaxf(mC, __shfl_xor(mC, 16)); mC = fmaxf(mC, __shfl_xor(mC, 32));
    nC = fminf(nC, __shfl_xor(nC, 16)); nC = fminf(nC, __shfl_xor(nC, 32));
    mM = fmaxf(mM, __shfl_xor(mM, 16)); mM = fmaxf(mM, __shfl_xor(mM, 32));
    mn = fminf(mn, nC);
    mx = fmaxf(mx, mM);
    float nM1 = fmaxf(M1, mS), nM2 = fmaxf(M2, mC);
    float sc1 = __expf(M1 - nM1), sc2 = __expf(M2 - nM2);
    M1 = nM1; M2 = nM2;
    float ps1 = 0.f, ps2 = 0.f;
    unsigned pk1[8], pk2[8];
    #pragma unroll
    for (int jf = 0; jf < 4; ++jf) {
      #pragma unroll
      for (int r = 0; r < 4; ++r) {
        float p1 = __expf(s1[jf][r] - nM1); s1[jf][r] = p1;
        float p2 = __expf(s2[jf][r] - nM2); s2[jf][r] = p2;
      }
      ps1 += (s1[jf][0] + s1[jf][1]) + (s1[jf][2] + s1[jf][3]);
      ps2 += (s2[jf][0] + s2[jf][1]) + (s2[jf][2] + s2[jf][3]);
      pk1[jf * 2]     = packf16(s1[jf][0], s1[jf][1]);
      pk1[jf * 2 + 1] = packf16(s1[jf][2], s1[jf][3]);
      pk2[jf * 2]     = packf16(s2[jf][0], s2[jf][1]);
      pk2[jf * 2 + 1] = packf16(s2[jf][2], s2[jf][3]);
    }
    ps1 += __shfl_xor(ps1, 16); ps1 += __shfl_xor(ps1, 32);
    ps2 += __shfl_xor(ps2, 16); ps2 += __shfl_xor(ps2, 32);
    S1 = S1 * sc1 + ps1;
    S2 = S2 * sc2 + ps2;

    // ---- P redistribution: C-layout -> B-frags, in-register ----
    // word(ks,t): keys 32ks+8lk+2t,+2t+1 = pk[2ks + (lk>>1)][t&1] @ lane srcl[t]
    union { unsigned u[4]; f16x8 v; } pb1[2], pb2[2];
    #pragma unroll
    for (int ks = 0; ks < 2; ++ks)
      #pragma unroll
      for (int tt = 0; tt < 4; ++tt) {
        unsigned va = (unsigned)__builtin_amdgcn_ds_bpermute(srcl[tt], (int)pk1[(2*ks)   * 2 + (tt & 1)]);
        unsigned vb = (unsigned)__builtin_amdgcn_ds_bpermute(srcl[tt], (int)pk1[(2*ks+1) * 2 + (tt & 1)]);
        pb1[ks].u[tt] = hi2 ? vb : va;
        va = (unsigned)__builtin_amdgcn_ds_bpermute(srcl[tt], (int)pk2[(2*ks)   * 2 + (tt & 1)]);
        vb = (unsigned)__builtin_amdgcn_ds_bpermute(srcl[tt], (int)pk2[(2*ks+1) * 2 + (tt & 1)]);
        pb2[ks].u[tt] = hi2 ? vb : va;
      }

    // ---- rescale O, then PV (swapped): O[d][q] ----
    #pragma unroll
    for (int df = 0; df < 4; ++df) { O1[df] *= sc1; O2[df] *= sc2; }
    #pragma unroll
    for (int ks = 0; ks < 2; ++ks) {
      #pragma unroll
      for (int df = 0; df < 4; ++df) {
        const int vb_ = (df * 16 + lq) * 64;
        f16x8 aV  = *reinterpret_cast<const f16x8*>(&VTb[vb_ + xo[ks]]);
        f16x8 aVC = *reinterpret_cast<const f16x8*>(&VCb[vb_ + xo[ks]]);
        O1[df] = MFMA(aV,  pb1[ks].v, O1[df]);
        O2[df] = MFMA(aVC, pb2[ks].v, O2[df]);
      }
    }
    __syncthreads();   // drains stage(t+1) vmem; all waves done with buf[cur]
    cur ^= 1;
  }

  // ---- partial store: [unit][64 rows][136]: O1(64) O2(64) state(6) ----
  {
    float* prow = part + (size_t)((h * 36 + qt) * NSPLIT + sp) * (64 * 136)
                       + (size_t)(w * 16 + lq) * 136;
    #pragma unroll
    for (int df = 0; df < 4; ++df) {
      *reinterpret_cast<f32x4*>(prow + df * 16 + lk * 4)      = O1[df];
      *reinterpret_cast<f32x4*>(prow + 64 + df * 16 + lk * 4) = O2[df];
    }
    if (lk == 0) {
      prow[128] = M1; prow[129] = S1; prow[130] = M2;
      prow[131] = S2; prow[132] = mn; prow[133] = mx;
    }
  }
  #undef STAGE
}

// ---------------------------------------------------------------------------
// merge2: combine NSPLIT partials per (h,qt), apply gvm, write mid (f16).
// grid (36, 8) x 256: thread = (row 0..63) x (16-d segment 0..3)
// ---------------------------------------------------------------------------
__global__ __launch_bounds__(256) void merge2(
    const float* __restrict__ part, const float* __restrict__ mask,
    f16* __restrict__ mid)
{
  const int qt = blockIdx.x, h = blockIdx.y;
  const int tid = threadIdx.x;
  const int r = tid >> 2, ds = (tid & 3) * 16;
  const float* p0 = part + (size_t)((h * 36 + qt) * NSPLIT + 0) * (64 * 136) + (size_t)r * 136;
  const float* p1 = part + (size_t)((h * 36 + qt) * NSPLIT + 1) * (64 * 136) + (size_t)r * 136;

  float M1a = p0[128], S1a = p0[129], M2a = p0[130], S2a = p0[131];
  float M1b = p1[128], S1b = p1[129], M2b = p1[130], S2b = p1[131];
  float mn = fminf(p0[132], p1[132]);
  float mx = fmaxf(p0[133], p1[133]);
  float nM1 = fmaxf(M1a, M1b), nM2 = fmaxf(M2a, M2b);
  float e1a = __expf(M1a - nM1), e1b = __expf(M1b - nM1);
  float e2a = __expf(M2a - nM2), e2b = __expf(M2b - nM2);
  float S1 = S1a * e1a + S1b * e1b;
  float S2 = S2a * e2a + S2b * e2b;

  int n = qt * 64 + r;
  float mv = mask[n];
  float mm = (mv < 0.5f) ? 1.0f : (mv > 0.5f ? -1.0f : -mv);
  float gvm = (mn - mx) * mm;
  float A1 = nM1 + gvm, A2 = nM2;
  float Mf = fmaxf(A1, A2);
  float w1 = __expf(A1 - Mf), w2 = __expf(A2 - Mf);
  float inv = 1.0f / (w1 * S1 + w2 * S2);

  f16 ov[16];
  #pragma unroll
  for (int c = 0; c < 4; ++c) {
    float4 o1a = *reinterpret_cast<const float4*>(p0 + ds + c * 4);
    float4 o1b = *reinterpret_cast<const float4*>(p1 + ds + c * 4);
    float4 o2a = *reinterpret_cast<const float4*>(p0 + 64 + ds + c * 4);
    float4 o2b = *reinterpret_cast<const float4*>(p1 + 64 + ds + c * 4);
    float v0 = (w1 * (o1a.x * e1a + o1b.x * e1b) + w2 * (o2a.x * e2a + o2b.x * e2b)) * inv;
    float v1 = (w1 * (o1a.y * e1a + o1b.y * e1b) + w2 * (o2a.y * e2a + o2b.y * e2b)) * inv;
    float v2 = (w1 * (o1a.z * e1a + o1b.z * e1b) + w2 * (o2a.z * e2a + o2b.z * e2b)) * inv;
    float v3 = (w1 * (o1a.w * e1a + o1b.w * e1b) + w2 * (o2a.w * e2a + o2b.w * e2b)) * inv;
    ov[c * 4] = (f16)v0; ov[c * 4 + 1] = (f16)v1;
    ov[c * 4 + 2] = (f16)v2; ov[c * 4 + 3] = (f16)v3;
  }
  f16* dst = mid + (size_t)n * INNER + h * 64 + ds;
  *reinterpret_cast<f16x8*>(dst)     = *reinterpret_cast<f16x8*>(&ov[0]);
  *reinterpret_cast<f16x8*>(dst + 8) = *reinterpret_cast<f16x8*>(&ov[8]);
}

// ---------------------------------------------------------------------------
// out_mfma: out = mid(f16) @ Wo + bo.  grid (144, 5), 64 threads (1 wave).
// ---------------------------------------------------------------------------
__global__ __launch_bounds__(64) void out_mfma(
    const f16* __restrict__ mid, const f16* __restrict__ WoT,
    const float* __restrict__ bo, float* __restrict__ out)
{
  const int n0 = blockIdx.x * 16;
  const int o0 = blockIdx.y * 64;
  const int l = threadIdx.x, lq = l & 15, lk = l >> 4;
  f32x4 acc[4] = {};
  const f16* arow = mid + (size_t)(n0 + lq) * INNER;
  #pragma unroll
  for (int ks = 0; ks < 16; ++ks) {
    f16x8 a = *reinterpret_cast<const f16x8*>(&arow[ks * 32 + lk * 8]);
    #pragma unroll
    for (int df = 0; df < 4; ++df) {
      f16x8 b = *reinterpret_cast<const f16x8*>(
          &WoT[(size_t)(o0 + df * 16 + lq) * INNER + ks * 32 + lk * 8]);
      acc[df] = MFMA(a, b, acc[df]);
    }
  }
  #pragma unroll
  for (int df = 0; df < 4; ++df) {
    float bb = bo[o0 + df * 16 + lq];
    #pragma unroll
    for (int r = 0; r < 4; ++r) {
      int n = n0 + lk * 4 + r;
      out[(size_t)n * QD + o0 + df * 16 + lq] = acc[df][r] + bb;
    }
  }
}

// ---------------------------------------------------------------------------
extern "C" void kernel_launch(void* const* d_in, const int* in_sizes, int n_in,
                              void* d_out, int out_size, void* d_ws, size_t ws_size,
                              hipStream_t stream) {
  const float* x    = (const float*)d_in[0];
  const float* Wq   = (const float*)d_in[1];
  const float* Wo   = (const float*)d_in[2];
  const float* bo   = (const float*)d_in[3];
  const float* qinj = (const float*)d_in[4];
  const float* kinj = (const float*)d_in[5];
  const float* vinj = (const float*)d_in[6];
  const float* kcnt = (const float*)d_in[7];
  const float* vcnt = (const float*)d_in[8];
  const float* mask = (const float*)d_in[9];
  float* out = (float*)d_out;

  const size_t T = (size_t)HEADS * NTOK * DH;   // 1179648
  f16* qhat = (f16*)d_ws;
  f16* qc16 = qhat + T;
  f16* k16  = qc16 + T;
  f16* kc16 = k16  + T;
  f16* vt16 = kc16 + T;
  f16* vct16= vt16 + T;
  f16* mid  = vct16 + T;                 // [2304][512] f16
  f16* x16  = mid;                       // aliased: dead before attn writes mid
  f16* WqT  = mid + 737280;
  f16* WoT  = mid + T;
  float* part = (float*)(WoT + 163840);  // 576 units x 64 x 136 f32 (~20 MB)

  prep_cvt   <<<2088, 256, 0, stream>>>(qinj, kinj, kcnt, x, qc16, k16, kc16, x16);
  prep_tr    <<<dim3(36, 8, 2), 256, 0, stream>>>(vinj, vcnt, vt16, vct16);
  prep_trW   <<<dim3(40, 2), 256, 0, stream>>>(Wq, Wo, WqT, WoT);
  qblend_mfma<<<dim3(72, 8), 256, 0, stream>>>(x16, WqT, qinj, qhat);
  attn_part  <<<576, 256, 0, stream>>>(qhat, qc16, k16, kc16, vt16, vct16, part);
  merge2     <<<dim3(36, 8), 256, 0, stream>>>(part, mask, mid);
  out_mfma   <<<dim3(144, 5), 64, 0, stream>>>(mid, WoT, bo, out);
}

// Round 6
// 99.661 us; speedup vs baseline: 13.6528x; 1.2142x over previous
//
#include <hip/hip_runtime.h>
#include <math.h>

#define HEADS 8
#define NTOK  2304
#define DH    64
#define QD    320
#define INNER 512
#define TPS   18     // key tiles per split (36 total, 2 splits)
#define PSTR  68     // part row stride (floats)

typedef _Float16 f16;
typedef f16  f16x4 __attribute__((ext_vector_type(4)));
typedef f16  f16x8 __attribute__((ext_vector_type(8)));
typedef float f32x4 __attribute__((ext_vector_type(4)));

#define MFMA(a,b,c) __builtin_amdgcn_mfma_f32_16x16x32_f16((a),(b),(c),0,0,0)

#define GLDS(gp, lp) __builtin_amdgcn_global_load_lds(                      \
    (const __attribute__((address_space(1))) void*)(gp),                    \
    (__attribute__((address_space(3))) void*)(lp), 16, 0, 0)

#if __has_builtin(__builtin_amdgcn_exp2f)
#define EXP2(x) __builtin_amdgcn_exp2f(x)
#else
#define EXP2(x) exp2f(x)
#endif

#define LOG2E 1.44269504f

static __device__ __forceinline__ unsigned pkrtz(float a, float b) {
#if __has_builtin(__builtin_amdgcn_cvt_pkrtz)
  return __builtin_bit_cast(unsigned, __builtin_amdgcn_cvt_pkrtz(a, b));
#else
  union { f16 h[2]; unsigned u; } c;
  c.h[0] = (f16)a; c.h[1] = (f16)b;
  return c.u;
#endif
}

// ---------------------------------------------------------------------------
// prep_all: fused prep. blocks [0,2088): f32->f16 converts
//   qinj->qc16 (x1), kinj->k16 (x1), kcnt->kc16 (x0.125*log2e), x->x16 (x1)
// blocks [2088,2664): v/vcnt -> f16 transposed [h][d][n]
// blocks [2664,2744): Wq -> WqT f16, Wo -> WoT f16
// ---------------------------------------------------------------------------
__global__ __launch_bounds__(256) void prep_all(
    const float* __restrict__ qi, const float* __restrict__ ki,
    const float* __restrict__ kc, const float* __restrict__ x,
    const float* __restrict__ v,  const float* __restrict__ vc,
    const float* __restrict__ Wq, const float* __restrict__ Wo,
    f16* __restrict__ oq, f16* __restrict__ ok, f16* __restrict__ okc,
    f16* __restrict__ ox, f16* __restrict__ vt, f16* __restrict__ vct,
    f16* __restrict__ WqT, f16* __restrict__ WoT)
{
  __shared__ float T[64][65];
  const int bid = blockIdx.x;
  const int tid = threadIdx.x;

  if (bid < 2088) {                       // ---- flat cvt ----
    int i = bid * 256 + tid;
    const float* src; f16* dst; float s = 1.0f; int off;
    if (i < 147456)      { src = qi; dst = oq;  off = i; }
    else if (i < 294912) { src = ki; dst = ok;  off = i - 147456; }
    else if (i < 442368) { src = kc; dst = okc; off = i - 294912; s = 0.125f * LOG2E; }
    else                 { src = x;  dst = ox;  off = i - 442368; }
    float4 a = reinterpret_cast<const float4*>(src)[off * 2];
    float4 b = reinterpret_cast<const float4*>(src)[off * 2 + 1];
    f16x8 o;
    o[0] = (f16)(a.x * s); o[1] = (f16)(a.y * s);
    o[2] = (f16)(a.z * s); o[3] = (f16)(a.w * s);
    o[4] = (f16)(b.x * s); o[5] = (f16)(b.y * s);
    o[6] = (f16)(b.z * s); o[7] = (f16)(b.w * s);
    *reinterpret_cast<f16x8*>(&dst[(size_t)off * 8]) = o;
  } else if (bid < 2664) {                // ---- V transpose ----
    int t = bid - 2088;
    int z = t / 288, rem = t % 288;
    int h = rem / 36, nt = rem % 36;
    const float* src = z ? vc : v;
    f16* dst = z ? vct : vt;
    const int n0 = nt * 64;
    const size_t base = ((size_t)h * NTOK + n0) * DH;
    for (int it = 0; it < 4; ++it) {
      int idx = tid + it * 256;
      int n = idx >> 4, d0 = (idx & 15) * 4;
      float4 a = *reinterpret_cast<const float4*>(&src[base + (size_t)n * DH + d0]);
      T[n][d0] = a.x; T[n][d0 + 1] = a.y; T[n][d0 + 2] = a.z; T[n][d0 + 3] = a.w;
    }
    __syncthreads();
    for (int it = 0; it < 2; ++it) {
      int idx = tid + it * 256;
      int d = idx >> 3, c0 = (idx & 7) * 8;
      f16x8 o;
      #pragma unroll
      for (int i = 0; i < 8; ++i) o[i] = (f16)T[c0 + i][d];
      *reinterpret_cast<f16x8*>(&dst[(size_t)(h * 64 + d) * NTOK + n0 + c0]) = o;
    }
  } else {                                // ---- weight transpose ----
    int t = bid - 2664;
    int z = t / 40, b = t % 40;
    const float* src = z ? Wo : Wq;
    f16* dst = z ? WoT : WqT;
    const int R = z ? INNER : QD;
    const int C = z ? QD : INNER;
    const int ctiles = C >> 6;
    const int rt = b / ctiles, ct = b % ctiles;
    for (int it = 0; it < 4; ++it) {
      int idx = tid + it * 256;
      int r = idx >> 4, c4 = (idx & 15) * 4;
      float4 a = *reinterpret_cast<const float4*>(&src[(size_t)(rt * 64 + r) * C + ct * 64 + c4]);
      T[r][c4] = a.x; T[r][c4 + 1] = a.y; T[r][c4 + 2] = a.z; T[r][c4 + 3] = a.w;
    }
    __syncthreads();
    for (int it = 0; it < 4; ++it) {
      int idx = tid + it * 256;
      int c = idx >> 4, r4 = (idx & 15) * 4;
      f16x4 o;
      #pragma unroll
      for (int i = 0; i < 4; ++i) o[i] = (f16)T[r4 + i][c];
      *reinterpret_cast<f16x4*>(&dst[(size_t)(ct * 64 + c) * R + rt * 64 + r4]) = o;
    }
  }
}

// ---------------------------------------------------------------------------
// qblend_mfma: qhat = (qinj + x@Wq) * 0.09375 * log2e  (f16, exp2-folded)
// ---------------------------------------------------------------------------
__global__ __launch_bounds__(256) void qblend_mfma(
    const f16* __restrict__ x16, const f16* __restrict__ WqT,
    const float* __restrict__ qinj, f16* __restrict__ qhat)
{
  const int qt = blockIdx.x, h = blockIdx.y;
  const int n0 = qt * 32;
  const int tid = threadIdx.x;
  const int w = tid >> 6, l = tid & 63, lq = l & 15, lk = l >> 4;
  const int qsub = w & 1, ch = w >> 1;
  f32x4 acc[2] = {};
  const f16* arow = x16 + (size_t)(n0 + qsub * 16 + lq) * QD;
  #pragma unroll
  for (int ks = 0; ks < 10; ++ks) {
    f16x8 a = *reinterpret_cast<const f16x8*>(&arow[ks * 32 + lk * 8]);
    #pragma unroll
    for (int df = 0; df < 2; ++df) {
      const f16* brow = WqT + (size_t)(h * 64 + ch * 32 + df * 16 + lq) * QD;
      f16x8 b = *reinterpret_cast<const f16x8*>(&brow[ks * 32 + lk * 8]);
      acc[df] = MFMA(a, b, acc[df]);
    }
  }
  const float sc = 0.09375f * LOG2E;
  #pragma unroll
  for (int df = 0; df < 2; ++df)
    #pragma unroll
    for (int r = 0; r < 4; ++r) {
      int n = n0 + qsub * 16 + lk * 4 + r;
      int d = ch * 32 + df * 16 + lq;
      size_t idx = ((size_t)h * NTOK + n) * DH + d;
      qhat[idx] = (f16)(sc * (qinj[idx] + acc[df][r]));
    }
}

// ---------------------------------------------------------------------------
// attn_sc: stream-split fused attention. Each block handles ONE stream:
//   strm=0 (style):   s1=K*qhat (+ s3=K*qc for mx), PV over V
//   strm=1 (content): s2=KC*qc (scaled, tracks mn), PV over VC
// grid 1152: h=bid&7 (XCD pin), strm=(bid>>3)&1, sp=(bid>>4)&1, qt=bid>>5.
// 2-phase LDS pipeline (32 KB dbuf, global_load_lds w/ XOR-swizzled source).
// 4 waves x 16 q-rows; swapped MFMA; P in-register via pkrtz + ds_bpermute.
// Partials (O, M, S, aux) per (stream,split) -> part[].
// ---------------------------------------------------------------------------
__global__ __launch_bounds__(256, 4) void attn_sc(
    const f16* __restrict__ qhat, const f16* __restrict__ qc16,
    const f16* __restrict__ k16,  const f16* __restrict__ kc16,
    const f16* __restrict__ vt16, const f16* __restrict__ vct16,
    float* __restrict__ part)
{
  __shared__ f16 smem[2][2][4096];   // [buf][K|V][64x64]

  const int bid = blockIdx.x;
  const int h    = bid & 7;
  const int strm = (bid >> 3) & 1;
  const int sp   = (bid >> 4) & 1;
  const int qt   = bid >> 5;
  const int tid = threadIdx.x;
  const int w = tid >> 6, l = tid & 63;
  const int lq = l & 15, lk = l >> 4;
  const size_t hb = (size_t)h * NTOK * DH;
  const int nrow = qt * 64 + w * 16 + lq;

  // Q fragments (B-operand, 16B contiguous per lane)
  f16x8 qB[2], qcB[2];
  {
    const size_t qr = hb + (size_t)nrow * DH;
    #pragma unroll
    for (int ks = 0; ks < 2; ++ks)
      qcB[ks] = *reinterpret_cast<const f16x8*>(&qc16[qr + ks * 32 + lk * 8]);
    if (!strm) {
      #pragma unroll
      for (int ks = 0; ks < 2; ++ks)
        qB[ks] = *reinterpret_cast<const f16x8*>(&qhat[qr + ks * 32 + lk * 8]);
    } else { qB[0] = qcB[0]; qB[1] = qcB[1]; }
  }

  // staging geometry (linear dest + inverse-swizzled source; read re-swizzles)
  const int row0 = tid >> 3, sl0 = tid & 7;
  const int sw0 = (sl0 ^ (row0 & 7)) * 8;          // f16 offset in 64-elem row
  const int row1 = 32 + row0;
  const f16* gK = (strm ? kc16 : k16) + hb;
  const f16* gV = (strm ? vct16 : vt16) + (size_t)h * DH * NTOK;
  const int lb = __builtin_amdgcn_readfirstlane((tid & 192) * 8);

  #define STAGE(nb, j0)                                                     \
    do {                                                                    \
      GLDS(gK + (size_t)((j0) + row0) * 64 + sw0, &smem[nb][0][lb]);        \
      GLDS(gK + (size_t)((j0) + row1) * 64 + sw0, &smem[nb][0][2048 + lb]); \
      GLDS(gV + (size_t)row0 * NTOK + (j0) + sw0, &smem[nb][1][lb]);        \
      GLDS(gV + (size_t)row1 * NTOK + (j0) + sw0, &smem[nb][1][2048 + lb]); \
    } while (0)

  const int swz = (lq & 7) * 8;
  int xo[2];
  #pragma unroll
  for (int ks = 0; ks < 2; ++ks) xo[ks] = ((ks * 32 + lk * 8) ^ swz);

  // bpermute source lanes (byte addresses) for P redistribution
  int srcl[4];
  #pragma unroll
  for (int t = 0; t < 4; ++t)
    srcl[t] = (lq + 16 * (2 * (lk & 1) + (t >> 1))) * 4;
  const int hi2 = lk >> 1;

  float M = -INFINITY, S = 0.f;
  float aux = strm ? INFINITY : -INFINITY;   // mn (content) / mx (style)
  f32x4 O[4] = {};

  STAGE(0, sp * (TPS * 64));
  __syncthreads();

  int cur = 0;
  for (int t = 0; t < TPS; ++t) {
    const int j0 = (sp * TPS + t) * 64;
    if (t < TPS - 1) STAGE(cur ^ 1, j0 + 64);

    const f16* Kb = &smem[cur][0][0];
    const f16* Vb = &smem[cur][1][0];

    // ---- scores (swapped MFMA): s[key][q] ----
    f32x4 s[4] = {};
    float tAux;
    if (!strm) {
      float mM = -INFINITY;
      #pragma unroll
      for (int jf = 0; jf < 4; ++jf) {
        f32x4 t3 = {};
        const int rb = (jf * 16 + lq) * 64;
        #pragma unroll
        for (int ks = 0; ks < 2; ++ks) {
          f16x8 aK = *reinterpret_cast<const f16x8*>(&Kb[rb + xo[ks]]);
          s[jf] = MFMA(aK, qB[ks], s[jf]);
          t3    = MFMA(aK, qcB[ks], t3);
        }
        mM = fmaxf(mM, fmaxf(fmaxf(t3[0], t3[1]), fmaxf(t3[2], t3[3])));
      }
      tAux = mM;
    } else {
      #pragma unroll
      for (int jf = 0; jf < 4; ++jf) {
        const int rb = (jf * 16 + lq) * 64;
        #pragma unroll
        for (int ks = 0; ks < 2; ++ks) {
          f16x8 aK = *reinterpret_cast<const f16x8*>(&Kb[rb + xo[ks]]);
          s[jf] = MFMA(aK, qcB[ks], s[jf]);
        }
      }
      float a0 = fminf(fminf(s[0][0], s[0][1]), fminf(s[0][2], s[0][3]));
      float a1 = fminf(fminf(s[1][0], s[1][1]), fminf(s[1][2], s[1][3]));
      float a2 = fminf(fminf(s[2][0], s[2][1]), fminf(s[2][2], s[2][3]));
      float a3 = fminf(fminf(s[3][0], s[3][1]), fminf(s[3][2], s[3][3]));
      tAux = fminf(fminf(a0, a1), fminf(a2, a3));
    }

    // ---- row-max + aux reduce (in-lane 16 + 2 shfls) ----
    float b0 = fmaxf(fmaxf(s[0][0], s[0][1]), fmaxf(s[0][2], s[0][3]));
    float b1 = fmaxf(fmaxf(s[1][0], s[1][1]), fmaxf(s[1][2], s[1][3]));
    float b2 = fmaxf(fmaxf(s[2][0], s[2][1]), fmaxf(s[2][2], s[2][3]));
    float b3 = fmaxf(fmaxf(s[3][0], s[3][1]), fmaxf(s[3][2], s[3][3]));
    float mS = fmaxf(fmaxf(b0, b1), fmaxf(b2, b3));
    mS = fmaxf(mS, __shfl_xor(mS, 16)); mS = fmaxf(mS, __shfl_xor(mS, 32));
    if (!strm) {
      tAux = fmaxf(tAux, __shfl_xor(tAux, 16));
      tAux = fmaxf(tAux, __shfl_xor(tAux, 32));
      aux = fmaxf(aux, tAux);
    } else {
      tAux = fminf(tAux, __shfl_xor(tAux, 16));
      tAux = fminf(tAux, __shfl_xor(tAux, 32));
      aux = fminf(aux, tAux);
    }

    // ---- online softmax (exp2 domain — log2e pre-folded into scores) ----
    float nM = fmaxf(M, mS);
    float sc = EXP2(M - nM);
    M = nM;
    float ps = 0.f;
    unsigned pk[8];
    #pragma unroll
    for (int jf = 0; jf < 4; ++jf) {
      #pragma unroll
      for (int r = 0; r < 4; ++r) {
        float p = EXP2(s[jf][r] - nM); s[jf][r] = p;
      }
      ps += (s[jf][0] + s[jf][1]) + (s[jf][2] + s[jf][3]);
      pk[jf * 2]     = pkrtz(s[jf][0], s[jf][1]);
      pk[jf * 2 + 1] = pkrtz(s[jf][2], s[jf][3]);
    }
    ps += __shfl_xor(ps, 16); ps += __shfl_xor(ps, 32);
    S = S * sc + ps;

    // ---- P redistribution: C-layout -> B-frags, in-register ----
    union { unsigned u[4]; f16x8 v; } pb[2];
    #pragma unroll
    for (int ks = 0; ks < 2; ++ks)
      #pragma unroll
      for (int tt = 0; tt < 4; ++tt) {
        unsigned va = (unsigned)__builtin_amdgcn_ds_bpermute(srcl[tt], (int)pk[(2 * ks)     * 2 + (tt & 1)]);
        unsigned vb = (unsigned)__builtin_amdgcn_ds_bpermute(srcl[tt], (int)pk[(2 * ks + 1) * 2 + (tt & 1)]);
        pb[ks].u[tt] = hi2 ? vb : va;
      }

    // ---- rescale O, then PV (swapped): O[d][q] ----
    #pragma unroll
    for (int df = 0; df < 4; ++df) O[df] *= sc;
    #pragma unroll
    for (int ks = 0; ks < 2; ++ks) {
      #pragma unroll
      for (int df = 0; df < 4; ++df) {
        const int vb_ = (df * 16 + lq) * 64;
        f16x8 aV = *reinterpret_cast<const f16x8*>(&Vb[vb_ + xo[ks]]);
        O[df] = MFMA(aV, pb[ks].v, O[df]);
      }
    }
    __syncthreads();   // drains stage(t+1) vmem; all waves done with buf[cur]
    cur ^= 1;
  }

  // ---- partial store: unit = (qt*8+h)*4 + strm*2 + sp; row stride PSTR ----
  {
    const size_t u = (size_t)((qt * 8 + h) * 4 + strm * 2 + sp);
    float* prow = part + u * (64 * PSTR) + (size_t)(w * 16 + lq) * PSTR;
    #pragma unroll
    for (int df = 0; df < 4; ++df)
      *reinterpret_cast<f32x4*>(prow + df * 16 + lk * 4) = O[df];
    if (lk == 0) { prow[64] = M; prow[65] = S; prow[66] = aux; }
  }
  #undef STAGE
}

// ---------------------------------------------------------------------------
// merge4: combine 2 splits x 2 streams per (h,qt), apply gvm, write mid f16.
// grid (36, 8) x 256: thread = (row 0..63) x (16-d segment 0..3)
// ---------------------------------------------------------------------------
__global__ __launch_bounds__(256) void merge4(
    const float* __restrict__ part, const float* __restrict__ mask,
    f16* __restrict__ mid)
{
  const int qt = blockIdx.x, h = blockIdx.y;
  const int tid = threadIdx.x;
  const int r = tid >> 2, ds = (tid & 3) * 16;
  const size_t base = (size_t)((qt * 8 + h) * 4) * (64 * PSTR);
  const float* pA0 = part + base + (size_t)r * PSTR;            // style sp0
  const float* pA1 = pA0 + 64 * PSTR;                           // style sp1
  const float* pB0 = pA1 + 64 * PSTR;                           // content sp0
  const float* pB1 = pB0 + 64 * PSTR;                           // content sp1

  float M1a = pA0[64], S1a = pA0[65], M1b = pA1[64], S1b = pA1[65];
  float M2a = pB0[64], S2a = pB0[65], M2b = pB1[64], S2b = pB1[65];
  float mx = fmaxf(pA0[66], pA1[66]);          // orig units (unscaled s3)
  float mn = fminf(pB0[66], pB1[66]);          // log2e-scaled units
  float nM1 = fmaxf(M1a, M1b), nM2 = fmaxf(M2a, M2b);
  float e1a = exp2f(M1a - nM1), e1b = exp2f(M1b - nM1);
  float e2a = exp2f(M2a - nM2), e2b = exp2f(M2b - nM2);
  float S1 = S1a * e1a + S1b * e1b;
  float S2 = S2a * e2a + S2b * e2b;

  int n = qt * 64 + r;
  float mv = mask[n];
  float mm = (mv < 0.5f) ? 1.0f : (mv > 0.5f ? -1.0f : -mv);
  float gvm = (mn - mx * LOG2E) * mm;          // in exp2 domain
  float A1 = nM1 + gvm, A2 = nM2;
  float Mf = fmaxf(A1, A2);
  float w1 = exp2f(A1 - Mf), w2 = exp2f(A2 - Mf);
  float inv = 1.0f / (w1 * S1 + w2 * S2);

  f16 ov[16];
  #pragma unroll
  for (int c = 0; c < 4; ++c) {
    float4 o1a = *reinterpret_cast<const float4*>(pA0 + ds + c * 4);
    float4 o1b = *reinterpret_cast<const float4*>(pA1 + ds + c * 4);
    float4 o2a = *reinterpret_cast<const float4*>(pB0 + ds + c * 4);
    float4 o2b = *reinterpret_cast<const float4*>(pB1 + ds + c * 4);
    ov[c*4+0] = (f16)((w1 * (o1a.x * e1a + o1b.x * e1b) + w2 * (o2a.x * e2a + o2b.x * e2b)) * inv);
    ov[c*4+1] = (f16)((w1 * (o1a.y * e1a + o1b.y * e1b) + w2 * (o2a.y * e2a + o2b.y * e2b)) * inv);
    ov[c*4+2] = (f16)((w1 * (o1a.z * e1a + o1b.z * e1b) + w2 * (o2a.z * e2a + o2b.z * e2b)) * inv);
    ov[c*4+3] = (f16)((w1 * (o1a.w * e1a + o1b.w * e1b) + w2 * (o2a.w * e2a + o2b.w * e2b)) * inv);
  }
  f16* dst = mid + (size_t)n * INNER + h * 64 + ds;
  *reinterpret_cast<f16x8*>(dst)     = *reinterpret_cast<f16x8*>(&ov[0]);
  *reinterpret_cast<f16x8*>(dst + 8) = *reinterpret_cast<f16x8*>(&ov[8]);
}

// ---------------------------------------------------------------------------
// out_mfma: out = mid(f16) @ Wo + bo.  grid (144, 5), 64 threads (1 wave).
// ---------------------------------------------------------------------------
__global__ __launch_bounds__(64) void out_mfma(
    const f16* __restrict__ mid, const f16* __restrict__ WoT,
    const float* __restrict__ bo, float* __restrict__ out)
{
  const int n0 = blockIdx.x * 16;
  const int o0 = blockIdx.y * 64;
  const int l = threadIdx.x, lq = l & 15, lk = l >> 4;
  f32x4 acc[4] = {};
  const f16* arow = mid + (size_t)(n0 + lq) * INNER;
  #pragma unroll
  for (int ks = 0; ks < 16; ++ks) {
    f16x8 a = *reinterpret_cast<const f16x8*>(&arow[ks * 32 + lk * 8]);
    #pragma unroll
    for (int df = 0; df < 4; ++df) {
      f16x8 b = *reinterpret_cast<const f16x8*>(
          &WoT[(size_t)(o0 + df * 16 + lq) * INNER + ks * 32 + lk * 8]);
      acc[df] = MFMA(a, b, acc[df]);
    }
  }
  #pragma unroll
  for (int df = 0; df < 4; ++df) {
    float bb = bo[o0 + df * 16 + lq];
    #pragma unroll
    for (int r = 0; r < 4; ++r) {
      int n = n0 + lk * 4 + r;
      out[(size_t)n * QD + o0 + df * 16 + lq] = acc[df][r] + bb;
    }
  }
}

// ---------------------------------------------------------------------------
extern "C" void kernel_launch(void* const* d_in, const int* in_sizes, int n_in,
                              void* d_out, int out_size, void* d_ws, size_t ws_size,
                              hipStream_t stream) {
  const float* x    = (const float*)d_in[0];
  const float* Wq   = (const float*)d_in[1];
  const float* Wo   = (const float*)d_in[2];
  const float* bo   = (const float*)d_in[3];
  const float* qinj = (const float*)d_in[4];
  const float* kinj = (const float*)d_in[5];
  const float* vinj = (const float*)d_in[6];
  const float* kcnt = (const float*)d_in[7];
  const float* vcnt = (const float*)d_in[8];
  const float* mask = (const float*)d_in[9];
  float* out = (float*)d_out;

  const size_t T = (size_t)HEADS * NTOK * DH;   // 1179648
  f16* qhat = (f16*)d_ws;
  f16* qc16 = qhat + T;
  f16* k16  = qc16 + T;
  f16* kc16 = k16  + T;
  f16* vt16 = kc16 + T;
  f16* vct16= vt16 + T;
  f16* mid  = vct16 + T;                 // [2304][512] f16
  f16* x16  = mid;                       // aliased: dead before merge4 writes mid
  f16* WqT  = mid + 737280;
  f16* WoT  = mid + T;
  float* part = (float*)(WoT + 163840);  // 1152 units x 64 x PSTR f32 (~20 MB)

  prep_all   <<<2744, 256, 0, stream>>>(qinj, kinj, kcnt, x, vinj, vcnt, Wq, Wo,
                                        qc16, k16, kc16, x16, vt16, vct16, WqT, WoT);
  qblend_mfma<<<dim3(72, 8), 256, 0, stream>>>(x16, WqT, qinj, qhat);
  attn_sc    <<<1152, 256, 0, stream>>>(qhat, qc16, k16, kc16, vt16, vct16, part);
  merge4     <<<dim3(36, 8), 256, 0, stream>>>(part, mask, mid);
  out_mfma   <<<dim3(144, 5), 64, 0, stream>>>(mid, WoT, bo, out);
}